// Round 10
// baseline (301.948 us; speedup 1.0000x reference)
//
#include <hip/hip_runtime.h>
#include <math.h>

// ---------------------------------------------------------------------------
// GATv2 2-layer GNN, fp32 in/out. N=50000, E=800000, F=128.
// 9 dispatches: memset -> count+prep_w (stores per-edge rank) -> scan_blocksum
//   -> scan_apply2 -> scatter (atomic-free, u16 csr) -> GEMM1 -> agg1 ->
//   GEMM2 -> agg2
// r8: xl stored bf16 RNE (gather bytes halved). r9: atomic-free u16 scatter.
// r10: GEMM tile M=64 -> M=32 (grid 782 -> 1563). r9 counters showed the
//   GEMM occupancy-starved (22.6% occ, MfmaUtil 7%, 85% idle): 782 blocks =
//   3/CU was the binding limit. M=32 + 17KB LDS doubles the wave pool.
//   Chunk-0 B-frag loads hoisted before the barrier (L2 latency overlaps).
// Falsified: grid.sync fusion (r5), split-operand GEMM (r4), agg SW-pipeline
//   (r1/r2), 1-block scan (r6), B double-buffering (guide m131 + r1/r2).
// ---------------------------------------------------------------------------

typedef short bf16x8 __attribute__((ext_vector_type(8)));
typedef float f32x4 __attribute__((ext_vector_type(4)));

// ---------------------------------------------------------------------------
// count degrees + store rank (blocks [0,nCnt)) ; split W -> bf16 hi/lo
// [n][k] (last 32 blocks).
// ---------------------------------------------------------------------------
__global__ __launch_bounds__(256) void count_prep_kernel(
    const int* __restrict__ dst, int* __restrict__ deg,
    unsigned short* __restrict__ rank16, int E, int nCnt,
    const float* __restrict__ W0, const float* __restrict__ W1,
    const float* __restrict__ W2, const float* __restrict__ W3,
    short* __restrict__ wt) {
    if ((int)blockIdx.x < nCnt) {
        int i = blockIdx.x * 256 + threadIdx.x;
        if (i < E) {
            int r = atomicAdd(&deg[dst[i]], 1);
            rank16[i] = (unsigned short)r;
        }
    } else {
        int b = blockIdx.x - nCnt;           // 0..31
        int mat = b >> 3, chunk = b & 7;
        const float* W = (mat == 0) ? W0 : (mat == 1) ? W1 : (mat == 2) ? W2 : W3;
        short* hi = wt + (size_t)mat * 2 * 16384;
        short* lo = hi + 16384;
        int i0 = chunk * 2048;
        for (int i = i0 + threadIdx.x; i < i0 + 2048; i += 256) {
            int k = i >> 7, n = i & 127;
            float x = W[i];
            unsigned u = __float_as_uint(x);
            unsigned hu = u & 0xFFFF0000u;
            float lf = x - __uint_as_float(hu);
            hi[n * 128 + k] = (short)(hu >> 16);
            lo[n * 128 + k] = (short)(__float_as_uint(lf) >> 16);
        }
    }
}

// --- scan pass 1 -- per-block (256 nodes) sums ---
__global__ __launch_bounds__(256) void scan_blocksum_kernel(const int* __restrict__ deg,
                                                            int* __restrict__ blockSums, int n) {
    __shared__ int wsum[4];
    int tid = threadIdx.x;
    int idx = blockIdx.x * 256 + tid;
    int v = (idx < n) ? deg[idx] : 0;
    int lane = tid & 63, wid = tid >> 6;
    #pragma unroll
    for (int off = 32; off > 0; off >>= 1) v += __shfl_xor(v, off);
    if (lane == 0) wsum[wid] = v;
    __syncthreads();
    if (tid == 0) blockSums[blockIdx.x] = wsum[0] + wsum[1] + wsum[2] + wsum[3];
}

// --- scan pass 2 (fused): block offset by direct reduction over blockSums
//     (nBlk <= 256) + local scan -> row_ptr. Block 0 writes total.
__global__ __launch_bounds__(256) void scan_apply2_kernel(
    const int* __restrict__ deg, const int* __restrict__ blockSums,
    int* __restrict__ row_ptr, int n, int nBlk) {
    __shared__ int sPre[4], sAll[4], wsum[4];
    int tid = threadIdx.x, lane = tid & 63, wid = tid >> 6;

    int bsv = (tid < nBlk) ? blockSums[tid] : 0;
    int pre = (tid < (int)blockIdx.x) ? bsv : 0;
    int all = bsv;
    #pragma unroll
    for (int off = 32; off > 0; off >>= 1) {
        pre += __shfl_xor(pre, off);
        all += __shfl_xor(all, off);
    }
    if (lane == 0) { sPre[wid] = pre; sAll[wid] = all; }
    __syncthreads();
    int off0 = sPre[0] + sPre[1] + sPre[2] + sPre[3];
    int total = sAll[0] + sAll[1] + sAll[2] + sAll[3];

    int idx = blockIdx.x * 256 + tid;
    int v = (idx < n) ? deg[idx] : 0;
    int incl = v;
    #pragma unroll
    for (int off = 1; off < 64; off <<= 1) {
        int t = __shfl_up(incl, off);
        if (lane >= off) incl += t;
    }
    if (lane == 63) wsum[wid] = incl;
    __syncthreads();
    int woff = 0;
    #pragma unroll
    for (int w = 0; w < 4; ++w) woff += (w < wid) ? wsum[w] : 0;
    int excl = off0 + woff + (incl - v);
    if (idx < n) row_ptr[idx] = excl;
    if (blockIdx.x == 0 && tid == 0) row_ptr[n] = total;
}

// --- atomic-free scatter: pos = row_ptr[dst] + rank16, csr entry = u16 src ---
__global__ void scatter_edges_kernel(const int* __restrict__ src, const int* __restrict__ dst,
                                     const int* __restrict__ row_ptr,
                                     const unsigned short* __restrict__ rank16,
                                     unsigned short* __restrict__ csr16, int E) {
    int i = blockIdx.x * blockDim.x + threadIdx.x;
    if (i < E) {
        int d = dst[i];
        int pos = row_ptr[d] + (int)rank16[i];
        csr16[pos] = (unsigned short)src[i];
    }
}

// ---------------------------------------------------------------------------
// One-barrier split-bf16 MFMA GEMM, dual-output 32x256 tile:
//   xl-plane (p=0) -> bf16 RNE [Nrows][128]; xr-plane (p=1) -> fp32.
// M=32: grid 1563 blocks (6.1/CU), LDS 17 KB -> occupancy cap ~76%
//   (r9's M=64 was 3 blocks/CU = 22.6% occ, 85% idle).
// Phase 1: stage 32x128 A-tile (4 float4/thread), split -> Ahi/Alo (stride
//   136). Chunk-0 B frags loaded BEFORE the single barrier. Phase 2: 4
//   K-chunks pure compute; 24 MFMA + 4 ds_read_b128 + 8 B-loads per wave.
// ---------------------------------------------------------------------------
#define LDK 136
__global__ __launch_bounds__(256) void gemm_mfma_dual32_kernel(
    const float* __restrict__ X, const short* __restrict__ wtL,
    const float* __restrict__ b0, short* __restrict__ out0bf,
    const float* __restrict__ b1, float* __restrict__ out1,
    int Nrows) {
    __shared__ __attribute__((aligned(16))) short Ahi[32][LDK];
    __shared__ __attribute__((aligned(16))) short Alo[32][LDK];

    int tid = threadIdx.x;
    int w = tid >> 6, lane = tid & 63, q = lane >> 4, tr = lane & 15;
    int m0 = blockIdx.x * 32;
    int n0 = w * 32;

    // --- B frags for chunk 0, issued before staging/barrier (L2 overlap) ---
    bf16x8 bh[4], bl[4];
    #pragma unroll
    for (int p = 0; p < 2; ++p) {
        const short* base = wtL + (size_t)p * 2 * 16384;
        #pragma unroll
        for (int nt = 0; nt < 2; ++nt) {
            size_t boff = (size_t)(n0 + nt * 16 + tr) * 128 + q * 8;
            bh[p * 2 + nt] = *(const bf16x8*)&base[boff];
            bl[p * 2 + nt] = *(const bf16x8*)&base[16384 + boff];
        }
    }

    // --- phase 1: stage 32x128 A-tile, 16 floats per thread ---
    {
        int srow = tid >> 3;            // 0..31
        int c0 = (tid & 7) * 16;        // 0,16,...,112
        int gr = m0 + srow; if (gr >= Nrows) gr = Nrows - 1;  // stores guarded later
        const float* xp = &X[(size_t)gr * 128 + c0];
        float4 v[4];
        #pragma unroll
        for (int j = 0; j < 4; ++j) v[j] = *(const float4*)(xp + j * 4);
        #pragma unroll
        for (int j = 0; j < 2; ++j) {
            bf16x8 hv, lv;
            #pragma unroll
            for (int k = 0; k < 2; ++k) {
                float4 vv = v[j * 2 + k];
                float f[4] = {vv.x, vv.y, vv.z, vv.w};
                #pragma unroll
                for (int e = 0; e < 4; ++e) {
                    unsigned u = __float_as_uint(f[e]);
                    unsigned hu = u & 0xFFFF0000u;
                    float lf = f[e] - __uint_as_float(hu);
                    hv[k * 4 + e] = (short)(hu >> 16);
                    lv[k * 4 + e] = (short)(__float_as_uint(lf) >> 16);
                }
            }
            *(bf16x8*)&Ahi[srow][c0 + j * 8] = hv;
            *(bf16x8*)&Alo[srow][c0 + j * 8] = lv;
        }
    }
    __syncthreads();

    // --- phase 2: pure compute ---
    f32x4 acc[2][4];   // [mt][p*2+nt]
    #pragma unroll
    for (int a = 0; a < 2; ++a)
        #pragma unroll
        for (int b = 0; b < 4; ++b) acc[a][b] = (f32x4){0.f, 0.f, 0.f, 0.f};

    for (int kc = 0; kc < 128; kc += 32) {
        #pragma unroll
        for (int mt = 0; mt < 2; ++mt) {
            bf16x8 ah = *(const bf16x8*)&Ahi[mt * 16 + tr][kc + q * 8];
            bf16x8 al = *(const bf16x8*)&Alo[mt * 16 + tr][kc + q * 8];
            #pragma unroll
            for (int j = 0; j < 4; ++j) {
                acc[mt][j] = __builtin_amdgcn_mfma_f32_16x16x32_bf16(ah, bh[j], acc[mt][j], 0, 0, 0);
                acc[mt][j] = __builtin_amdgcn_mfma_f32_16x16x32_bf16(ah, bl[j], acc[mt][j], 0, 0, 0);
                acc[mt][j] = __builtin_amdgcn_mfma_f32_16x16x32_bf16(al, bh[j], acc[mt][j], 0, 0, 0);
            }
        }
        // B frags for next chunk (loads overlap the MFMAs above via scheduler)
        if (kc < 96) {
            #pragma unroll
            for (int p = 0; p < 2; ++p) {
                const short* base = wtL + (size_t)p * 2 * 16384;
                #pragma unroll
                for (int nt = 0; nt < 2; ++nt) {
                    size_t boff = (size_t)(n0 + nt * 16 + tr) * 128 + (kc + 32) + q * 8;
                    bh[p * 2 + nt] = *(const bf16x8*)&base[boff];
                    bl[p * 2 + nt] = *(const bf16x8*)&base[16384 + boff];
                }
            }
        }
    }

    // epilogue: D layout col = tr, row = q*4 + r
    // p=0 (xl): bf16 RNE store. p=1 (xr): fp32 store.
    #pragma unroll
    for (int nt = 0; nt < 2; ++nt) {
        float bv0 = b0[n0 + nt * 16 + tr];
        float bv1 = b1[n0 + nt * 16 + tr];
        #pragma unroll
        for (int mt = 0; mt < 2; ++mt) {
            #pragma unroll
            for (int r = 0; r < 4; ++r) {
                int row = m0 + mt * 16 + q * 4 + r;
                if (row < Nrows) {
                    float v0 = acc[mt][nt][r] + bv0;
                    unsigned u = __float_as_uint(v0);
                    unsigned rb = (u + 0x7FFFu + ((u >> 16) & 1u)) >> 16;
                    out0bf[(size_t)row * 128 + n0 + nt * 16 + tr] = (short)rb;
                    out1[(size_t)row * 128 + n0 + nt * 16 + tr] = acc[mt][2 + nt][r] + bv1;
                }
            }
        }
    }
}
#undef LDK

// ---------------------------------------------------------------------------
// Aggregation v6: xl is bf16 [N][128], csr entries u16. 16-lane groups,
// 4 edges/wave. Lane qlane holds features [qlane*8, qlane*8+8): ONE 16B load
// per edge-row. Per-edge reduce: 4 intra-16 shfl_xor (DPP). xor16/32 hoisted.
// ---------------------------------------------------------------------------
__global__ __launch_bounds__(256) void gat_aggregate_kernel(
    const short* __restrict__ xl16, const float* __restrict__ xr,
    const float* __restrict__ att, const float* __restrict__ bias,
    const int* __restrict__ row_ptr, const unsigned short* __restrict__ csr16,
    float* __restrict__ out, int N, int applyRelu) {
    int wid = threadIdx.x >> 6;      // 0..3 -> node within block
    int lane = threadIdx.x & 63;
    int qlane = lane & 15;
    int qid = lane >> 4;
    int node = blockIdx.x * 4 + wid;
    if (node >= N) return;

    const bf16x8* xlb = (const bf16x8*)xl16;   // row = 16 x bf16x8
    float4 xrA = ((const float4*)xr)[(size_t)node * 32 + qlane * 2];
    float4 xrB = ((const float4*)xr)[(size_t)node * 32 + qlane * 2 + 1];
    float4 atA = ((const float4*)att)[qlane * 2];
    float4 atB = ((const float4*)att)[qlane * 2 + 1];

    int beg = row_ptr[node];
    int end = row_ptr[node + 1];

    float dsum = 0.f;
    float4 accA = {0.f, 0.f, 0.f, 0.f};
    float4 accB = {0.f, 0.f, 0.f, 0.f};

    for (int cbase = beg; cbase < end; cbase += 64) {
        int cnt = end - cbase;
        if (cnt > 64) cnt = 64;
        int myidx = (lane < cnt) ? (int)csr16[cbase + lane] : 0;  // coalesced u16
        int nq = (cnt + 3) >> 2;                                  // quads of 4 edges

        for (int g = 0; g < nq; ++g) {
            int eidx = 4 * g + qid;
            int s = __shfl(myidx, eidx);
            bf16x8 mv = xlb[((size_t)s << 4) + qlane];
            float4 vA, vB;
            vA.x = __uint_as_float(((unsigned)(unsigned short)mv[0]) << 16);
            vA.y = __uint_as_float(((unsigned)(unsigned short)mv[1]) << 16);
            vA.z = __uint_as_float(((unsigned)(unsigned short)mv[2]) << 16);
            vA.w = __uint_as_float(((unsigned)(unsigned short)mv[3]) << 16);
            vB.x = __uint_as_float(((unsigned)(unsigned short)mv[4]) << 16);
            vB.y = __uint_as_float(((unsigned)(unsigned short)mv[5]) << 16);
            vB.z = __uint_as_float(((unsigned)(unsigned short)mv[6]) << 16);
            vB.w = __uint_as_float(((unsigned)(unsigned short)mv[7]) << 16);

            float t, p;
            t = vA.x + xrA.x; t = t > 0.f ? t : 0.2f * t; p = t * atA.x;
            t = vA.y + xrA.y; t = t > 0.f ? t : 0.2f * t; p = fmaf(t, atA.y, p);
            t = vA.z + xrA.z; t = t > 0.f ? t : 0.2f * t; p = fmaf(t, atA.z, p);
            t = vA.w + xrA.w; t = t > 0.f ? t : 0.2f * t; p = fmaf(t, atA.w, p);
            t = vB.x + xrB.x; t = t > 0.f ? t : 0.2f * t; p = fmaf(t, atB.x, p);
            t = vB.y + xrB.y; t = t > 0.f ? t : 0.2f * t; p = fmaf(t, atB.y, p);
            t = vB.z + xrB.z; t = t > 0.f ? t : 0.2f * t; p = fmaf(t, atB.z, p);
            t = vB.w + xrB.w; t = t > 0.f ? t : 0.2f * t; p = fmaf(t, atB.w, p);

            p += __shfl_xor(p, 1);
            p += __shfl_xor(p, 2);
            p += __shfl_xor(p, 4);
            p += __shfl_xor(p, 8);

            float e = (eidx < cnt) ? __expf(p) : 0.f;
            dsum += e;
            accA.x = fmaf(e, vA.x, accA.x);
            accA.y = fmaf(e, vA.y, accA.y);
            accA.z = fmaf(e, vA.z, accA.z);
            accA.w = fmaf(e, vA.w, accA.w);
            accB.x = fmaf(e, vB.x, accB.x);
            accB.y = fmaf(e, vB.y, accB.y);
            accB.z = fmaf(e, vB.z, accB.z);
            accB.w = fmaf(e, vB.w, accB.w);
        }
    }

    #pragma unroll
    for (int off = 16; off <= 32; off <<= 1) {
        dsum += __shfl_xor(dsum, off);
        accA.x += __shfl_xor(accA.x, off);
        accA.y += __shfl_xor(accA.y, off);
        accA.z += __shfl_xor(accA.z, off);
        accA.w += __shfl_xor(accA.w, off);
        accB.x += __shfl_xor(accB.x, off);
        accB.y += __shfl_xor(accB.y, off);
        accB.z += __shfl_xor(accB.z, off);
        accB.w += __shfl_xor(accB.w, off);
    }

    float inv = dsum > 0.f ? 1.f / dsum : 0.f;
    float4 bvA = ((const float4*)bias)[qlane * 2];
    float4 bvB = ((const float4*)bias)[qlane * 2 + 1];
    float4 oA, oB;
    oA.x = accA.x * inv + bvA.x; oA.y = accA.y * inv + bvA.y;
    oA.z = accA.z * inv + bvA.z; oA.w = accA.w * inv + bvA.w;
    oB.x = accB.x * inv + bvB.x; oB.y = accB.y * inv + bvB.y;
    oB.z = accB.z * inv + bvB.z; oB.w = accB.w * inv + bvB.w;
    if (applyRelu) {
        oA.x = fmaxf(oA.x, 0.f); oA.y = fmaxf(oA.y, 0.f);
        oA.z = fmaxf(oA.z, 0.f); oA.w = fmaxf(oA.w, 0.f);
        oB.x = fmaxf(oB.x, 0.f); oB.y = fmaxf(oB.y, 0.f);
        oB.z = fmaxf(oB.z, 0.f); oB.w = fmaxf(oB.w, 0.f);
    }
    if (lane < 16) {
        ((float4*)out)[(size_t)node * 32 + qlane * 2] = oA;
        ((float4*)out)[(size_t)node * 32 + qlane * 2 + 1] = oB;
    }
}

// ---------------------------------------------------------------------------

extern "C" void kernel_launch(void* const* d_in, const int* in_sizes, int n_in,
                              void* d_out, int out_size, void* d_ws, size_t ws_size,
                              hipStream_t stream) {
    const float* x    = (const float*)d_in[0];
    const int* eidx   = (const int*)d_in[1];
    const float* Wl1  = (const float*)d_in[2];
    const float* bl1  = (const float*)d_in[3];
    const float* Wr1  = (const float*)d_in[4];
    const float* br1  = (const float*)d_in[5];
    const float* att1 = (const float*)d_in[6];
    const float* b1   = (const float*)d_in[7];
    const float* Wl2  = (const float*)d_in[8];
    const float* bl2  = (const float*)d_in[9];
    const float* Wr2  = (const float*)d_in[10];
    const float* br2  = (const float*)d_in[11];
    const float* att2 = (const float*)d_in[12];
    const float* b2   = (const float*)d_in[13];

    const int N = in_sizes[0] / 128;
    const int E = in_sizes[1] / 2;
    const int* src = eidx;
    const int* dst = eidx + E;

    const int nBlk = (N + 255) / 256;

    // workspace layout
    size_t NF = (size_t)N * 128;
    short* xl16 = (short*)d_ws;               // bf16 xl plane [N][128]
    float* bufB = (float*)(xl16 + NF);        // xr fp32
    float* bufC = bufB + NF;                  // h fp32 (layer-1 out)
    int* deg       = (int*)(bufC + NF);       // [N]
    int* row_ptr   = deg + N;                 // [N+1]
    int* blockSums = row_ptr + (N + 1);       // [nBlk]
    unsigned short* rank16 = (unsigned short*)(blockSums + nBlk);  // [E]
    unsigned short* csr16  = rank16 + E;      // [E]
    short* wt      = (short*)(csr16 + E);     // 4 matrices x (hi+lo) x 16384

    float* outF = (float*)d_out;

    // --- CSR build + W prep (5 dispatches) ---
    const int nCnt = (E + 255) / 256;
    hipMemsetAsync(deg, 0, (size_t)N * sizeof(int), stream);
    count_prep_kernel<<<nCnt + 32, 256, 0, stream>>>(dst, deg, rank16, E, nCnt,
                                                     Wl1, Wr1, Wl2, Wr2, wt);
    scan_blocksum_kernel<<<nBlk, 256, 0, stream>>>(deg, blockSums, N);
    scan_apply2_kernel<<<nBlk, 256, 0, stream>>>(deg, blockSums, row_ptr, N, nBlk);
    scatter_edges_kernel<<<nCnt, 256, 0, stream>>>(src, dst, row_ptr, rank16, csr16, E);

    dim3 gemmGrid((N + 31) / 32);
    dim3 aggGrid((N + 3) / 4);

    // --- layer 1 ---
    gemm_mfma_dual32_kernel<<<gemmGrid, 256, 0, stream>>>(x, wt, bl1, xl16, br1, bufB, N);
    gat_aggregate_kernel<<<aggGrid, 256, 0, stream>>>(xl16, bufB, att1, b1, row_ptr, csr16,
                                                      bufC, N, 1);
    // --- layer 2 ---
    gemm_mfma_dual32_kernel<<<gemmGrid, 256, 0, stream>>>(bufC, wt + 2 * 2 * 16384, bl2, xl16,
                                                          br2, bufB, N);
    gat_aggregate_kernel<<<aggGrid, 256, 0, stream>>>(xl16, bufB, att2, b2, row_ptr, csr16,
                                                      outF, N, 0);
}

// Round 11
// 296.712 us; speedup vs baseline: 1.0176x; 1.0176x over previous
//
#include <hip/hip_runtime.h>
#include <math.h>

// ---------------------------------------------------------------------------
// GATv2 2-layer GNN, fp32 in/out. N=50000, E=800000, F=128.
// 9 dispatches: memset(deg8) -> count+prep_w (8-slice privatized histogram,
//   stores per-edge in-slice rank) -> scan_blocksum2 (per-node slice prefix ->
//   base8, dtot, blockSums) -> scan_apply2 (row_ptr + rpb = row_ptr+base8)
//   -> scatter (atomic-free: pos = rpb[slice][dst]+rank) -> GEMM1 -> agg1 ->
//   GEMM2 -> agg2
// r8: xl bf16 RNE (gather bytes halved). r9: atomic-free u16 scatter.
// r10: M=32 GEMM. r11: 8-slice degree count (slice = blockIdx&7 ~ XCD):
//   r10 showed count_prep = 46.8us @ 0.33% VALU -- cross-XCD atomic line
//   ping-pong. Slices keep each histogram line owned by one L2.
// agg: leaky = fmaxf(t, 0.2t) (1 op cheaper than select; identical values).
// Falsified: grid.sync fusion (r5), split-operand GEMM (r4), agg SW-pipeline
//   (r1/r2), 1-block scan (r6).
// ---------------------------------------------------------------------------

typedef short bf16x8 __attribute__((ext_vector_type(8)));
typedef float f32x4 __attribute__((ext_vector_type(4)));

// ---------------------------------------------------------------------------
// count degrees into 8 privatized slices + store in-slice rank (blocks
// [0,nCnt)); split W -> bf16 hi/lo [n][k] (last 32 blocks).
// ---------------------------------------------------------------------------
__global__ __launch_bounds__(256) void count_prep_kernel(
    const int* __restrict__ dst, int* __restrict__ deg8,
    unsigned short* __restrict__ rank16, int E, int N, int nCnt,
    const float* __restrict__ W0, const float* __restrict__ W1,
    const float* __restrict__ W2, const float* __restrict__ W3,
    short* __restrict__ wt) {
    if ((int)blockIdx.x < nCnt) {
        int i = blockIdx.x * 256 + threadIdx.x;
        if (i < E) {
            int slice = blockIdx.x & 7;
            int r = atomicAdd(&deg8[(size_t)slice * N + dst[i]], 1);
            rank16[i] = (unsigned short)r;
        }
    } else {
        int b = blockIdx.x - nCnt;           // 0..31
        int mat = b >> 3, chunk = b & 7;
        const float* W = (mat == 0) ? W0 : (mat == 1) ? W1 : (mat == 2) ? W2 : W3;
        short* hi = wt + (size_t)mat * 2 * 16384;
        short* lo = hi + 16384;
        int i0 = chunk * 2048;
        for (int i = i0 + threadIdx.x; i < i0 + 2048; i += 256) {
            int k = i >> 7, n = i & 127;
            float x = W[i];
            unsigned u = __float_as_uint(x);
            unsigned hu = u & 0xFFFF0000u;
            float lf = x - __uint_as_float(hu);
            hi[n * 128 + k] = (short)(hu >> 16);
            lo[n * 128 + k] = (short)(__float_as_uint(lf) >> 16);
        }
    }
}

// --- scan pass 1: per-node slice prefix (base8, u16), per-node total (dtot),
//     per-256-node block sums ---
__global__ __launch_bounds__(256) void scan_blocksum2_kernel(
    const int* __restrict__ deg8, unsigned short* __restrict__ base8,
    int* __restrict__ dtot, int* __restrict__ blockSums, int n) {
    __shared__ int wsum[4];
    int tid = threadIdx.x;
    int idx = blockIdx.x * 256 + tid;
    int lane = tid & 63, wid = tid >> 6;
    int tot = 0;
    if (idx < n) {
        int b = 0;
        #pragma unroll
        for (int s = 0; s < 8; ++s) {
            int v = deg8[(size_t)s * n + idx];
            base8[(size_t)s * n + idx] = (unsigned short)b;
            b += v;
        }
        tot = b;
        dtot[idx] = tot;
    }
    int v = tot;
    #pragma unroll
    for (int off = 32; off > 0; off >>= 1) v += __shfl_xor(v, off);
    if (lane == 0) wsum[wid] = v;
    __syncthreads();
    if (tid == 0) blockSums[blockIdx.x] = wsum[0] + wsum[1] + wsum[2] + wsum[3];
}

// --- scan pass 2 (fused): block offset by direct reduction over blockSums
//     (nBlk <= 256) + local scan -> row_ptr, rpb[s][n] = excl + base8[s][n].
__global__ __launch_bounds__(256) void scan_apply2_kernel(
    const int* __restrict__ dtot, const int* __restrict__ blockSums,
    const unsigned short* __restrict__ base8,
    int* __restrict__ row_ptr, int* __restrict__ rpb, int n, int nBlk) {
    __shared__ int sPre[4], sAll[4], wsum[4];
    int tid = threadIdx.x, lane = tid & 63, wid = tid >> 6;

    int bsv = (tid < nBlk) ? blockSums[tid] : 0;
    int pre = (tid < (int)blockIdx.x) ? bsv : 0;
    int all = bsv;
    #pragma unroll
    for (int off = 32; off > 0; off >>= 1) {
        pre += __shfl_xor(pre, off);
        all += __shfl_xor(all, off);
    }
    if (lane == 0) { sPre[wid] = pre; sAll[wid] = all; }
    __syncthreads();
    int off0 = sPre[0] + sPre[1] + sPre[2] + sPre[3];
    int total = sAll[0] + sAll[1] + sAll[2] + sAll[3];

    int idx = blockIdx.x * 256 + tid;
    int v = (idx < n) ? dtot[idx] : 0;
    int incl = v;
    #pragma unroll
    for (int off = 1; off < 64; off <<= 1) {
        int t = __shfl_up(incl, off);
        if (lane >= off) incl += t;
    }
    if (lane == 63) wsum[wid] = incl;
    __syncthreads();
    int woff = 0;
    #pragma unroll
    for (int w = 0; w < 4; ++w) woff += (w < wid) ? wsum[w] : 0;
    int excl = off0 + woff + (incl - v);
    if (idx < n) {
        row_ptr[idx] = excl;
        #pragma unroll
        for (int s = 0; s < 8; ++s)
            rpb[(size_t)s * n + idx] = excl + (int)base8[(size_t)s * n + idx];
    }
    if (blockIdx.x == 0 && tid == 0) row_ptr[n] = total;
}

// --- atomic-free scatter: slice recomputed from edge index (blockIdx&7);
//     pos = rpb[slice][dst] + rank16, csr entry = u16 src ---
__global__ void scatter_edges_kernel(const int* __restrict__ src, const int* __restrict__ dst,
                                     const int* __restrict__ rpb,
                                     const unsigned short* __restrict__ rank16,
                                     unsigned short* __restrict__ csr16, int E, int N) {
    int i = blockIdx.x * blockDim.x + threadIdx.x;
    if (i < E) {
        int d = dst[i];
        int slice = blockIdx.x & 7;
        int pos = rpb[(size_t)slice * N + d] + (int)rank16[i];
        csr16[pos] = (unsigned short)src[i];
    }
}

// ---------------------------------------------------------------------------
// One-barrier split-bf16 MFMA GEMM, dual-output 32x256 tile:
//   xl-plane (p=0) -> bf16 RNE [Nrows][128]; xr-plane (p=1) -> fp32.
// Phase 1: stage 32x128 A-tile, split -> Ahi/Alo (stride 136). Chunk-0 B
// frags loaded BEFORE the barrier. Phase 2: 4 K-chunks pure compute.
// ---------------------------------------------------------------------------
#define LDK 136
__global__ __launch_bounds__(256) void gemm_mfma_dual32_kernel(
    const float* __restrict__ X, const short* __restrict__ wtL,
    const float* __restrict__ b0, short* __restrict__ out0bf,
    const float* __restrict__ b1, float* __restrict__ out1,
    int Nrows) {
    __shared__ __attribute__((aligned(16))) short Ahi[32][LDK];
    __shared__ __attribute__((aligned(16))) short Alo[32][LDK];

    int tid = threadIdx.x;
    int w = tid >> 6, lane = tid & 63, q = lane >> 4, tr = lane & 15;
    int m0 = blockIdx.x * 32;
    int n0 = w * 32;

    // --- B frags for chunk 0, issued before staging/barrier (L2 overlap) ---
    bf16x8 bh[4], bl[4];
    #pragma unroll
    for (int p = 0; p < 2; ++p) {
        const short* base = wtL + (size_t)p * 2 * 16384;
        #pragma unroll
        for (int nt = 0; nt < 2; ++nt) {
            size_t boff = (size_t)(n0 + nt * 16 + tr) * 128 + q * 8;
            bh[p * 2 + nt] = *(const bf16x8*)&base[boff];
            bl[p * 2 + nt] = *(const bf16x8*)&base[16384 + boff];
        }
    }

    // --- phase 1: stage 32x128 A-tile, 16 floats per thread ---
    {
        int srow = tid >> 3;            // 0..31
        int c0 = (tid & 7) * 16;        // 0,16,...,112
        int gr = m0 + srow; if (gr >= Nrows) gr = Nrows - 1;  // stores guarded later
        const float* xp = &X[(size_t)gr * 128 + c0];
        float4 v[4];
        #pragma unroll
        for (int j = 0; j < 4; ++j) v[j] = *(const float4*)(xp + j * 4);
        #pragma unroll
        for (int j = 0; j < 2; ++j) {
            bf16x8 hv, lv;
            #pragma unroll
            for (int k = 0; k < 2; ++k) {
                float4 vv = v[j * 2 + k];
                float f[4] = {vv.x, vv.y, vv.z, vv.w};
                #pragma unroll
                for (int e = 0; e < 4; ++e) {
                    unsigned u = __float_as_uint(f[e]);
                    unsigned hu = u & 0xFFFF0000u;
                    float lf = f[e] - __uint_as_float(hu);
                    hv[k * 4 + e] = (short)(hu >> 16);
                    lv[k * 4 + e] = (short)(__float_as_uint(lf) >> 16);
                }
            }
            *(bf16x8*)&Ahi[srow][c0 + j * 8] = hv;
            *(bf16x8*)&Alo[srow][c0 + j * 8] = lv;
        }
    }
    __syncthreads();

    // --- phase 2: pure compute ---
    f32x4 acc[2][4];   // [mt][p*2+nt]
    #pragma unroll
    for (int a = 0; a < 2; ++a)
        #pragma unroll
        for (int b = 0; b < 4; ++b) acc[a][b] = (f32x4){0.f, 0.f, 0.f, 0.f};

    for (int kc = 0; kc < 128; kc += 32) {
        #pragma unroll
        for (int mt = 0; mt < 2; ++mt) {
            bf16x8 ah = *(const bf16x8*)&Ahi[mt * 16 + tr][kc + q * 8];
            bf16x8 al = *(const bf16x8*)&Alo[mt * 16 + tr][kc + q * 8];
            #pragma unroll
            for (int j = 0; j < 4; ++j) {
                acc[mt][j] = __builtin_amdgcn_mfma_f32_16x16x32_bf16(ah, bh[j], acc[mt][j], 0, 0, 0);
                acc[mt][j] = __builtin_amdgcn_mfma_f32_16x16x32_bf16(ah, bl[j], acc[mt][j], 0, 0, 0);
                acc[mt][j] = __builtin_amdgcn_mfma_f32_16x16x32_bf16(al, bh[j], acc[mt][j], 0, 0, 0);
            }
        }
        // B frags for next chunk (loads overlap the MFMAs above via scheduler)
        if (kc < 96) {
            #pragma unroll
            for (int p = 0; p < 2; ++p) {
                const short* base = wtL + (size_t)p * 2 * 16384;
                #pragma unroll
                for (int nt = 0; nt < 2; ++nt) {
                    size_t boff = (size_t)(n0 + nt * 16 + tr) * 128 + (kc + 32) + q * 8;
                    bh[p * 2 + nt] = *(const bf16x8*)&base[boff];
                    bl[p * 2 + nt] = *(const bf16x8*)&base[16384 + boff];
                }
            }
        }
    }

    // epilogue: D layout col = tr, row = q*4 + r
    // p=0 (xl): bf16 RNE store. p=1 (xr): fp32 store.
    #pragma unroll
    for (int nt = 0; nt < 2; ++nt) {
        float bv0 = b0[n0 + nt * 16 + tr];
        float bv1 = b1[n0 + nt * 16 + tr];
        #pragma unroll
        for (int mt = 0; mt < 2; ++mt) {
            #pragma unroll
            for (int r = 0; r < 4; ++r) {
                int row = m0 + mt * 16 + q * 4 + r;
                if (row < Nrows) {
                    float v0 = acc[mt][nt][r] + bv0;
                    unsigned u = __float_as_uint(v0);
                    unsigned rb = (u + 0x7FFFu + ((u >> 16) & 1u)) >> 16;
                    out0bf[(size_t)row * 128 + n0 + nt * 16 + tr] = (short)rb;
                    out1[(size_t)row * 128 + n0 + nt * 16 + tr] = acc[mt][2 + nt][r] + bv1;
                }
            }
        }
    }
}
#undef LDK

// ---------------------------------------------------------------------------
// Aggregation v6: xl is bf16 [N][128], csr entries u16. 16-lane groups,
// 4 edges/wave. Lane qlane holds features [qlane*8, qlane*8+8): ONE 16B load
// per edge-row. leaky = fmaxf(t, 0.2t). Per-edge reduce: 4 intra-16 shfl_xor.
// ---------------------------------------------------------------------------
__global__ __launch_bounds__(256) void gat_aggregate_kernel(
    const short* __restrict__ xl16, const float* __restrict__ xr,
    const float* __restrict__ att, const float* __restrict__ bias,
    const int* __restrict__ row_ptr, const unsigned short* __restrict__ csr16,
    float* __restrict__ out, int N, int applyRelu) {
    int wid = threadIdx.x >> 6;      // 0..3 -> node within block
    int lane = threadIdx.x & 63;
    int qlane = lane & 15;
    int qid = lane >> 4;
    int node = blockIdx.x * 4 + wid;
    if (node >= N) return;

    const bf16x8* xlb = (const bf16x8*)xl16;   // row = 16 x bf16x8
    float4 xrA = ((const float4*)xr)[(size_t)node * 32 + qlane * 2];
    float4 xrB = ((const float4*)xr)[(size_t)node * 32 + qlane * 2 + 1];
    float4 atA = ((const float4*)att)[qlane * 2];
    float4 atB = ((const float4*)att)[qlane * 2 + 1];

    int beg = row_ptr[node];
    int end = row_ptr[node + 1];

    float dsum = 0.f;
    float4 accA = {0.f, 0.f, 0.f, 0.f};
    float4 accB = {0.f, 0.f, 0.f, 0.f};

    for (int cbase = beg; cbase < end; cbase += 64) {
        int cnt = end - cbase;
        if (cnt > 64) cnt = 64;
        int myidx = (lane < cnt) ? (int)csr16[cbase + lane] : 0;  // coalesced u16
        int nq = (cnt + 3) >> 2;                                  // quads of 4 edges

        for (int g = 0; g < nq; ++g) {
            int eidx = 4 * g + qid;
            int s = __shfl(myidx, eidx);
            bf16x8 mv = xlb[((size_t)s << 4) + qlane];
            float4 vA, vB;
            vA.x = __uint_as_float(((unsigned)(unsigned short)mv[0]) << 16);
            vA.y = __uint_as_float(((unsigned)(unsigned short)mv[1]) << 16);
            vA.z = __uint_as_float(((unsigned)(unsigned short)mv[2]) << 16);
            vA.w = __uint_as_float(((unsigned)(unsigned short)mv[3]) << 16);
            vB.x = __uint_as_float(((unsigned)(unsigned short)mv[4]) << 16);
            vB.y = __uint_as_float(((unsigned)(unsigned short)mv[5]) << 16);
            vB.z = __uint_as_float(((unsigned)(unsigned short)mv[6]) << 16);
            vB.w = __uint_as_float(((unsigned)(unsigned short)mv[7]) << 16);

            float t, p;
            t = vA.x + xrA.x; t = fmaxf(t, 0.2f * t); p = t * atA.x;
            t = vA.y + xrA.y; t = fmaxf(t, 0.2f * t); p = fmaf(t, atA.y, p);
            t = vA.z + xrA.z; t = fmaxf(t, 0.2f * t); p = fmaf(t, atA.z, p);
            t = vA.w + xrA.w; t = fmaxf(t, 0.2f * t); p = fmaf(t, atA.w, p);
            t = vB.x + xrB.x; t = fmaxf(t, 0.2f * t); p = fmaf(t, atB.x, p);
            t = vB.y + xrB.y; t = fmaxf(t, 0.2f * t); p = fmaf(t, atB.y, p);
            t = vB.z + xrB.z; t = fmaxf(t, 0.2f * t); p = fmaf(t, atB.z, p);
            t = vB.w + xrB.w; t = fmaxf(t, 0.2f * t); p = fmaf(t, atB.w, p);

            p += __shfl_xor(p, 1);
            p += __shfl_xor(p, 2);
            p += __shfl_xor(p, 4);
            p += __shfl_xor(p, 8);

            float e = (eidx < cnt) ? __expf(p) : 0.f;
            dsum += e;
            accA.x = fmaf(e, vA.x, accA.x);
            accA.y = fmaf(e, vA.y, accA.y);
            accA.z = fmaf(e, vA.z, accA.z);
            accA.w = fmaf(e, vA.w, accA.w);
            accB.x = fmaf(e, vB.x, accB.x);
            accB.y = fmaf(e, vB.y, accB.y);
            accB.z = fmaf(e, vB.z, accB.z);
            accB.w = fmaf(e, vB.w, accB.w);
        }
    }

    #pragma unroll
    for (int off = 16; off <= 32; off <<= 1) {
        dsum += __shfl_xor(dsum, off);
        accA.x += __shfl_xor(accA.x, off);
        accA.y += __shfl_xor(accA.y, off);
        accA.z += __shfl_xor(accA.z, off);
        accA.w += __shfl_xor(accA.w, off);
        accB.x += __shfl_xor(accB.x, off);
        accB.y += __shfl_xor(accB.y, off);
        accB.z += __shfl_xor(accB.z, off);
        accB.w += __shfl_xor(accB.w, off);
    }

    float inv = dsum > 0.f ? 1.f / dsum : 0.f;
    float4 bvA = ((const float4*)bias)[qlane * 2];
    float4 bvB = ((const float4*)bias)[qlane * 2 + 1];
    float4 oA, oB;
    oA.x = accA.x * inv + bvA.x; oA.y = accA.y * inv + bvA.y;
    oA.z = accA.z * inv + bvA.z; oA.w = accA.w * inv + bvA.w;
    oB.x = accB.x * inv + bvB.x; oB.y = accB.y * inv + bvB.y;
    oB.z = accB.z * inv + bvB.z; oB.w = accB.w * inv + bvB.w;
    if (applyRelu) {
        oA.x = fmaxf(oA.x, 0.f); oA.y = fmaxf(oA.y, 0.f);
        oA.z = fmaxf(oA.z, 0.f); oA.w = fmaxf(oA.w, 0.f);
        oB.x = fmaxf(oB.x, 0.f); oB.y = fmaxf(oB.y, 0.f);
        oB.z = fmaxf(oB.z, 0.f); oB.w = fmaxf(oB.w, 0.f);
    }
    if (lane < 16) {
        ((float4*)out)[(size_t)node * 32 + qlane * 2] = oA;
        ((float4*)out)[(size_t)node * 32 + qlane * 2 + 1] = oB;
    }
}

// ---------------------------------------------------------------------------

extern "C" void kernel_launch(void* const* d_in, const int* in_sizes, int n_in,
                              void* d_out, int out_size, void* d_ws, size_t ws_size,
                              hipStream_t stream) {
    const float* x    = (const float*)d_in[0];
    const int* eidx   = (const int*)d_in[1];
    const float* Wl1  = (const float*)d_in[2];
    const float* bl1  = (const float*)d_in[3];
    const float* Wr1  = (const float*)d_in[4];
    const float* br1  = (const float*)d_in[5];
    const float* att1 = (const float*)d_in[6];
    const float* b1   = (const float*)d_in[7];
    const float* Wl2  = (const float*)d_in[8];
    const float* bl2  = (const float*)d_in[9];
    const float* Wr2  = (const float*)d_in[10];
    const float* br2  = (const float*)d_in[11];
    const float* att2 = (const float*)d_in[12];
    const float* b2   = (const float*)d_in[13];

    const int N = in_sizes[0] / 128;
    const int E = in_sizes[1] / 2;
    const int* src = eidx;
    const int* dst = eidx + E;

    const int nBlk = (N + 255) / 256;

    // workspace layout
    size_t NF = (size_t)N * 128;
    short* xl16 = (short*)d_ws;               // bf16 xl plane [N][128]
    float* bufB = (float*)(xl16 + NF);        // xr fp32
    float* bufC = bufB + NF;                  // h fp32 (layer-1 out)
    int* deg8      = (int*)(bufC + NF);       // [8][N]
    int* dtot      = deg8 + 8 * (size_t)N;    // [N]
    int* row_ptr   = dtot + N;                // [N+1]
    int* blockSums = row_ptr + (N + 1);       // [nBlk]
    int* rpb       = blockSums + nBlk;        // [8][N]
    unsigned short* base8  = (unsigned short*)(rpb + 8 * (size_t)N);  // [8][N]
    unsigned short* rank16 = base8 + 8 * (size_t)N;                   // [E]
    unsigned short* csr16  = rank16 + E;      // [E]
    short* wt      = (short*)(csr16 + E);     // 4 matrices x (hi+lo) x 16384

    float* outF = (float*)d_out;

    // --- CSR build + W prep (5 dispatches) ---
    const int nCnt = (E + 255) / 256;
    hipMemsetAsync(deg8, 0, 8 * (size_t)N * sizeof(int), stream);
    count_prep_kernel<<<nCnt + 32, 256, 0, stream>>>(dst, deg8, rank16, E, N, nCnt,
                                                     Wl1, Wr1, Wl2, Wr2, wt);
    scan_blocksum2_kernel<<<nBlk, 256, 0, stream>>>(deg8, base8, dtot, blockSums, N);
    scan_apply2_kernel<<<nBlk, 256, 0, stream>>>(dtot, blockSums, base8, row_ptr, rpb, N, nBlk);
    scatter_edges_kernel<<<nCnt, 256, 0, stream>>>(src, dst, rpb, rank16, csr16, E, N);

    dim3 gemmGrid((N + 31) / 32);
    dim3 aggGrid((N + 3) / 4);

    // --- layer 1 ---
    gemm_mfma_dual32_kernel<<<gemmGrid, 256, 0, stream>>>(x, wt, bl1, xl16, br1, bufB, N);
    gat_aggregate_kernel<<<aggGrid, 256, 0, stream>>>(xl16, bufB, att1, b1, row_ptr, csr16,
                                                      bufC, N, 1);
    // --- layer 2 ---
    gemm_mfma_dual32_kernel<<<gemmGrid, 256, 0, stream>>>(bufC, wt + 2 * 2 * 16384, bl2, xl16,
                                                          br2, bufB, N);
    gat_aggregate_kernel<<<aggGrid, 256, 0, stream>>>(xl16, bufB, att2, b2, row_ptr, csr16,
                                                      outF, N, 0);
}

// Round 12
// 294.342 us; speedup vs baseline: 1.0258x; 1.0081x over previous
//
#include <hip/hip_runtime.h>
#include <math.h>

// ---------------------------------------------------------------------------
// GATv2 2-layer GNN, fp32 in/out. N=50000, E=800000, F=128.
// 8 dispatches: prep_zero (W split + zero deg8) -> [GEMM1 || count] (grid-
//   fused: blocks 0..1562 = GEMM layer 1, blocks 1563.. = 8-slice degree
//   count; the two are data-independent so GEMM1's ~45us hides under count)
//   -> scan_blocksum2 -> scan_apply2 -> scatter (atomic-free, u16 csr)
//   -> agg1 -> GEMM2 -> agg2
// r8: xl bf16 RNE (gather bytes halved). r9: atomic-free u16 scatter.
// r11: 8-slice count. r12: GEMM1||count grid fusion (stream fork/join is
//   banned under graph capture -- hipEvent* -- so concurrency via one grid).
// slice = (edge>>8)&7 in BOTH count and scatter (must match).
// Falsified: grid.sync fusion (r5), split-operand GEMM (r4), agg SW-pipeline
//   (r1/r2), 1-block scan (r6), GEMM tile size as the GEMM lever (r9/r10).
// ---------------------------------------------------------------------------

typedef short bf16x8 __attribute__((ext_vector_type(8)));
typedef float f32x4 __attribute__((ext_vector_type(4)));

#define LDK 136

// ---------------------------------------------------------------------------
// prep_zero: 32 blocks. Splits the 4 W matrices into bf16 hi/lo [n][k]
// planes AND zeroes deg8 (replaces the memset dispatch).
// ---------------------------------------------------------------------------
__global__ __launch_bounds__(256) void prep_zero_kernel(
    const float* __restrict__ W0, const float* __restrict__ W1,
    const float* __restrict__ W2, const float* __restrict__ W3,
    short* __restrict__ wt, int* __restrict__ deg8, int total8N) {
    int b = blockIdx.x;                  // 0..31
    for (int j = b * 256 + threadIdx.x; j < total8N; j += 32 * 256) deg8[j] = 0;
    int mat = b >> 3, chunk = b & 7;
    const float* W = (mat == 0) ? W0 : (mat == 1) ? W1 : (mat == 2) ? W2 : W3;
    short* hi = wt + (size_t)mat * 2 * 16384;
    short* lo = hi + 16384;
    int i0 = chunk * 2048;
    for (int i = i0 + threadIdx.x; i < i0 + 2048; i += 256) {
        int k = i >> 7, n = i & 127;
        float x = W[i];
        unsigned u = __float_as_uint(x);
        unsigned hu = u & 0xFFFF0000u;
        float lf = x - __uint_as_float(hu);
        hi[n * 128 + k] = (short)(hu >> 16);
        lo[n * 128 + k] = (short)(__float_as_uint(lf) >> 16);
    }
}

// ---------------------------------------------------------------------------
// One-barrier split-bf16 MFMA GEMM body, dual-output 32x256 tile:
//   xl-plane (p=0) -> bf16 RNE [Nrows][128]; xr-plane (p=1) -> fp32.
// ---------------------------------------------------------------------------
__device__ __forceinline__ void gemm_dual32_body(
    int bx, const float* __restrict__ X, const short* __restrict__ wtL,
    const float* __restrict__ b0, short* __restrict__ out0bf,
    const float* __restrict__ b1, float* __restrict__ out1,
    int Nrows, short (&Ahi)[32][LDK], short (&Alo)[32][LDK]) {
    int tid = threadIdx.x;
    int w = tid >> 6, lane = tid & 63, q = lane >> 4, tr = lane & 15;
    int m0 = bx * 32;
    int n0 = w * 32;

    // B frags for chunk 0, issued before staging/barrier (L2 overlap)
    bf16x8 bh[4], bl[4];
    #pragma unroll
    for (int p = 0; p < 2; ++p) {
        const short* base = wtL + (size_t)p * 2 * 16384;
        #pragma unroll
        for (int nt = 0; nt < 2; ++nt) {
            size_t boff = (size_t)(n0 + nt * 16 + tr) * 128 + q * 8;
            bh[p * 2 + nt] = *(const bf16x8*)&base[boff];
            bl[p * 2 + nt] = *(const bf16x8*)&base[16384 + boff];
        }
    }

    // phase 1: stage 32x128 A-tile, 16 floats per thread
    {
        int srow = tid >> 3;            // 0..31
        int c0 = (tid & 7) * 16;        // 0,16,...,112
        int gr = m0 + srow; if (gr >= Nrows) gr = Nrows - 1;  // stores guarded later
        const float* xp = &X[(size_t)gr * 128 + c0];
        float4 v[4];
        #pragma unroll
        for (int j = 0; j < 4; ++j) v[j] = *(const float4*)(xp + j * 4);
        #pragma unroll
        for (int j = 0; j < 2; ++j) {
            bf16x8 hv, lv;
            #pragma unroll
            for (int k = 0; k < 2; ++k) {
                float4 vv = v[j * 2 + k];
                float f[4] = {vv.x, vv.y, vv.z, vv.w};
                #pragma unroll
                for (int e = 0; e < 4; ++e) {
                    unsigned u = __float_as_uint(f[e]);
                    unsigned hu = u & 0xFFFF0000u;
                    float lf = f[e] - __uint_as_float(hu);
                    hv[k * 4 + e] = (short)(hu >> 16);
                    lv[k * 4 + e] = (short)(__float_as_uint(lf) >> 16);
                }
            }
            *(bf16x8*)&Ahi[srow][c0 + j * 8] = hv;
            *(bf16x8*)&Alo[srow][c0 + j * 8] = lv;
        }
    }
    __syncthreads();

    // phase 2: pure compute
    f32x4 acc[2][4];   // [mt][p*2+nt]
    #pragma unroll
    for (int a = 0; a < 2; ++a)
        #pragma unroll
        for (int b = 0; b < 4; ++b) acc[a][b] = (f32x4){0.f, 0.f, 0.f, 0.f};

    for (int kc = 0; kc < 128; kc += 32) {
        #pragma unroll
        for (int mt = 0; mt < 2; ++mt) {
            bf16x8 ah = *(const bf16x8*)&Ahi[mt * 16 + tr][kc + q * 8];
            bf16x8 al = *(const bf16x8*)&Alo[mt * 16 + tr][kc + q * 8];
            #pragma unroll
            for (int j = 0; j < 4; ++j) {
                acc[mt][j] = __builtin_amdgcn_mfma_f32_16x16x32_bf16(ah, bh[j], acc[mt][j], 0, 0, 0);
                acc[mt][j] = __builtin_amdgcn_mfma_f32_16x16x32_bf16(ah, bl[j], acc[mt][j], 0, 0, 0);
                acc[mt][j] = __builtin_amdgcn_mfma_f32_16x16x32_bf16(al, bh[j], acc[mt][j], 0, 0, 0);
            }
        }
        if (kc < 96) {
            #pragma unroll
            for (int p = 0; p < 2; ++p) {
                const short* base = wtL + (size_t)p * 2 * 16384;
                #pragma unroll
                for (int nt = 0; nt < 2; ++nt) {
                    size_t boff = (size_t)(n0 + nt * 16 + tr) * 128 + (kc + 32) + q * 8;
                    bh[p * 2 + nt] = *(const bf16x8*)&base[boff];
                    bl[p * 2 + nt] = *(const bf16x8*)&base[16384 + boff];
                }
            }
        }
    }

    // epilogue: D layout col = tr, row = q*4 + r
    #pragma unroll
    for (int nt = 0; nt < 2; ++nt) {
        float bv0 = b0[n0 + nt * 16 + tr];
        float bv1 = b1[n0 + nt * 16 + tr];
        #pragma unroll
        for (int mt = 0; mt < 2; ++mt) {
            #pragma unroll
            for (int r = 0; r < 4; ++r) {
                int row = m0 + mt * 16 + q * 4 + r;
                if (row < Nrows) {
                    float v0 = acc[mt][nt][r] + bv0;
                    unsigned u = __float_as_uint(v0);
                    unsigned rb = (u + 0x7FFFu + ((u >> 16) & 1u)) >> 16;
                    out0bf[(size_t)row * 128 + n0 + nt * 16 + tr] = (short)rb;
                    out1[(size_t)row * 128 + n0 + nt * 16 + tr] = acc[mt][2 + nt][r] + bv1;
                }
            }
        }
    }
}

// --- standalone GEMM (layer 2) ---
__global__ __launch_bounds__(256) void gemm_mfma_dual32_kernel(
    const float* __restrict__ X, const short* __restrict__ wtL,
    const float* __restrict__ b0, short* __restrict__ out0bf,
    const float* __restrict__ b1, float* __restrict__ out1, int Nrows) {
    __shared__ __attribute__((aligned(16))) short Ahi[32][LDK];
    __shared__ __attribute__((aligned(16))) short Alo[32][LDK];
    gemm_dual32_body(blockIdx.x, X, wtL, b0, out0bf, b1, out1, Nrows, Ahi, Alo);
}

// --- fused: blocks [0,gemmBlocks) = GEMM layer 1; rest = 8-slice count ---
__global__ __launch_bounds__(256) void gemm1_count_kernel(
    const float* __restrict__ X, const short* __restrict__ wtL,
    const float* __restrict__ b0, short* __restrict__ out0bf,
    const float* __restrict__ b1, float* __restrict__ out1,
    int Nrows, int gemmBlocks,
    const int* __restrict__ dst, int* __restrict__ deg8,
    unsigned short* __restrict__ rank16, int E, int N) {
    __shared__ __attribute__((aligned(16))) short Ahi[32][LDK];
    __shared__ __attribute__((aligned(16))) short Alo[32][LDK];
    if ((int)blockIdx.x < gemmBlocks) {
        gemm_dual32_body(blockIdx.x, X, wtL, b0, out0bf, b1, out1, Nrows, Ahi, Alo);
    } else {
        int i = (blockIdx.x - gemmBlocks) * 256 + threadIdx.x;
        if (i < E) {
            int slice = (i >> 8) & 7;            // must match scatter
            int r = atomicAdd(&deg8[(size_t)slice * N + dst[i]], 1);
            rank16[i] = (unsigned short)r;
        }
    }
}

// --- scan pass 1: per-node slice prefix (base8, u16), per-node total (dtot),
//     per-256-node block sums ---
__global__ __launch_bounds__(256) void scan_blocksum2_kernel(
    const int* __restrict__ deg8, unsigned short* __restrict__ base8,
    int* __restrict__ dtot, int* __restrict__ blockSums, int n) {
    __shared__ int wsum[4];
    int tid = threadIdx.x;
    int idx = blockIdx.x * 256 + tid;
    int lane = tid & 63, wid = tid >> 6;
    int tot = 0;
    if (idx < n) {
        int b = 0;
        #pragma unroll
        for (int s = 0; s < 8; ++s) {
            int v = deg8[(size_t)s * n + idx];
            base8[(size_t)s * n + idx] = (unsigned short)b;
            b += v;
        }
        tot = b;
        dtot[idx] = tot;
    }
    int v = tot;
    #pragma unroll
    for (int off = 32; off > 0; off >>= 1) v += __shfl_xor(v, off);
    if (lane == 0) wsum[wid] = v;
    __syncthreads();
    if (tid == 0) blockSums[blockIdx.x] = wsum[0] + wsum[1] + wsum[2] + wsum[3];
}

// --- scan pass 2 (fused): block offset by direct reduction over blockSums
//     (nBlk <= 256) + local scan -> row_ptr, rpb[s][n] = excl + base8[s][n].
__global__ __launch_bounds__(256) void scan_apply2_kernel(
    const int* __restrict__ dtot, const int* __restrict__ blockSums,
    const unsigned short* __restrict__ base8,
    int* __restrict__ row_ptr, int* __restrict__ rpb, int n, int nBlk) {
    __shared__ int sPre[4], sAll[4], wsum[4];
    int tid = threadIdx.x, lane = tid & 63, wid = tid >> 6;

    int bsv = (tid < nBlk) ? blockSums[tid] : 0;
    int pre = (tid < (int)blockIdx.x) ? bsv : 0;
    int all = bsv;
    #pragma unroll
    for (int off = 32; off > 0; off >>= 1) {
        pre += __shfl_xor(pre, off);
        all += __shfl_xor(all, off);
    }
    if (lane == 0) { sPre[wid] = pre; sAll[wid] = all; }
    __syncthreads();
    int off0 = sPre[0] + sPre[1] + sPre[2] + sPre[3];
    int total = sAll[0] + sAll[1] + sAll[2] + sAll[3];

    int idx = blockIdx.x * 256 + tid;
    int v = (idx < n) ? dtot[idx] : 0;
    int incl = v;
    #pragma unroll
    for (int off = 1; off < 64; off <<= 1) {
        int t = __shfl_up(incl, off);
        if (lane >= off) incl += t;
    }
    if (lane == 63) wsum[wid] = incl;
    __syncthreads();
    int woff = 0;
    #pragma unroll
    for (int w = 0; w < 4; ++w) woff += (w < wid) ? wsum[w] : 0;
    int excl = off0 + woff + (incl - v);
    if (idx < n) {
        row_ptr[idx] = excl;
        #pragma unroll
        for (int s = 0; s < 8; ++s)
            rpb[(size_t)s * n + idx] = excl + (int)base8[(size_t)s * n + idx];
    }
    if (blockIdx.x == 0 && tid == 0) row_ptr[n] = total;
}

// --- atomic-free scatter: slice = (i>>8)&7 (matches count);
//     pos = rpb[slice][dst] + rank16, csr entry = u16 src ---
__global__ void scatter_edges_kernel(const int* __restrict__ src, const int* __restrict__ dst,
                                     const int* __restrict__ rpb,
                                     const unsigned short* __restrict__ rank16,
                                     unsigned short* __restrict__ csr16, int E, int N) {
    int i = blockIdx.x * blockDim.x + threadIdx.x;
    if (i < E) {
        int d = dst[i];
        int slice = (i >> 8) & 7;
        int pos = rpb[(size_t)slice * N + d] + (int)rank16[i];
        csr16[pos] = (unsigned short)src[i];
    }
}

// ---------------------------------------------------------------------------
// Aggregation v6: xl is bf16 [N][128], csr entries u16. 16-lane groups,
// 4 edges/wave. Lane qlane holds features [qlane*8, qlane*8+8): ONE 16B load
// per edge-row. leaky = fmaxf(t, 0.2t). Per-edge reduce: 4 intra-16 shfl_xor.
// ---------------------------------------------------------------------------
__global__ __launch_bounds__(256) void gat_aggregate_kernel(
    const short* __restrict__ xl16, const float* __restrict__ xr,
    const float* __restrict__ att, const float* __restrict__ bias,
    const int* __restrict__ row_ptr, const unsigned short* __restrict__ csr16,
    float* __restrict__ out, int N, int applyRelu) {
    int wid = threadIdx.x >> 6;      // 0..3 -> node within block
    int lane = threadIdx.x & 63;
    int qlane = lane & 15;
    int qid = lane >> 4;
    int node = blockIdx.x * 4 + wid;
    if (node >= N) return;

    const bf16x8* xlb = (const bf16x8*)xl16;   // row = 16 x bf16x8
    float4 xrA = ((const float4*)xr)[(size_t)node * 32 + qlane * 2];
    float4 xrB = ((const float4*)xr)[(size_t)node * 32 + qlane * 2 + 1];
    float4 atA = ((const float4*)att)[qlane * 2];
    float4 atB = ((const float4*)att)[qlane * 2 + 1];

    int beg = row_ptr[node];
    int end = row_ptr[node + 1];

    float dsum = 0.f;
    float4 accA = {0.f, 0.f, 0.f, 0.f};
    float4 accB = {0.f, 0.f, 0.f, 0.f};

    for (int cbase = beg; cbase < end; cbase += 64) {
        int cnt = end - cbase;
        if (cnt > 64) cnt = 64;
        int myidx = (lane < cnt) ? (int)csr16[cbase + lane] : 0;  // coalesced u16
        int nq = (cnt + 3) >> 2;                                  // quads of 4 edges

        for (int g = 0; g < nq; ++g) {
            int eidx = 4 * g + qid;
            int s = __shfl(myidx, eidx);
            bf16x8 mv = xlb[((size_t)s << 4) + qlane];
            float4 vA, vB;
            vA.x = __uint_as_float(((unsigned)(unsigned short)mv[0]) << 16);
            vA.y = __uint_as_float(((unsigned)(unsigned short)mv[1]) << 16);
            vA.z = __uint_as_float(((unsigned)(unsigned short)mv[2]) << 16);
            vA.w = __uint_as_float(((unsigned)(unsigned short)mv[3]) << 16);
            vB.x = __uint_as_float(((unsigned)(unsigned short)mv[4]) << 16);
            vB.y = __uint_as_float(((unsigned)(unsigned short)mv[5]) << 16);
            vB.z = __uint_as_float(((unsigned)(unsigned short)mv[6]) << 16);
            vB.w = __uint_as_float(((unsigned)(unsigned short)mv[7]) << 16);

            float t, p;
            t = vA.x + xrA.x; t = fmaxf(t, 0.2f * t); p = t * atA.x;
            t = vA.y + xrA.y; t = fmaxf(t, 0.2f * t); p = fmaf(t, atA.y, p);
            t = vA.z + xrA.z; t = fmaxf(t, 0.2f * t); p = fmaf(t, atA.z, p);
            t = vA.w + xrA.w; t = fmaxf(t, 0.2f * t); p = fmaf(t, atA.w, p);
            t = vB.x + xrB.x; t = fmaxf(t, 0.2f * t); p = fmaf(t, atB.x, p);
            t = vB.y + xrB.y; t = fmaxf(t, 0.2f * t); p = fmaf(t, atB.y, p);
            t = vB.z + xrB.z; t = fmaxf(t, 0.2f * t); p = fmaf(t, atB.z, p);
            t = vB.w + xrB.w; t = fmaxf(t, 0.2f * t); p = fmaf(t, atB.w, p);

            p += __shfl_xor(p, 1);
            p += __shfl_xor(p, 2);
            p += __shfl_xor(p, 4);
            p += __shfl_xor(p, 8);

            float e = (eidx < cnt) ? __expf(p) : 0.f;
            dsum += e;
            accA.x = fmaf(e, vA.x, accA.x);
            accA.y = fmaf(e, vA.y, accA.y);
            accA.z = fmaf(e, vA.z, accA.z);
            accA.w = fmaf(e, vA.w, accA.w);
            accB.x = fmaf(e, vB.x, accB.x);
            accB.y = fmaf(e, vB.y, accB.y);
            accB.z = fmaf(e, vB.z, accB.z);
            accB.w = fmaf(e, vB.w, accB.w);
        }
    }

    #pragma unroll
    for (int off = 16; off <= 32; off <<= 1) {
        dsum += __shfl_xor(dsum, off);
        accA.x += __shfl_xor(accA.x, off);
        accA.y += __shfl_xor(accA.y, off);
        accA.z += __shfl_xor(accA.z, off);
        accA.w += __shfl_xor(accA.w, off);
        accB.x += __shfl_xor(accB.x, off);
        accB.y += __shfl_xor(accB.y, off);
        accB.z += __shfl_xor(accB.z, off);
        accB.w += __shfl_xor(accB.w, off);
    }

    float inv = dsum > 0.f ? 1.f / dsum : 0.f;
    float4 bvA = ((const float4*)bias)[qlane * 2];
    float4 bvB = ((const float4*)bias)[qlane * 2 + 1];
    float4 oA, oB;
    oA.x = accA.x * inv + bvA.x; oA.y = accA.y * inv + bvA.y;
    oA.z = accA.z * inv + bvA.z; oA.w = accA.w * inv + bvA.w;
    oB.x = accB.x * inv + bvB.x; oB.y = accB.y * inv + bvB.y;
    oB.z = accB.z * inv + bvB.z; oB.w = accB.w * inv + bvB.w;
    if (applyRelu) {
        oA.x = fmaxf(oA.x, 0.f); oA.y = fmaxf(oA.y, 0.f);
        oA.z = fmaxf(oA.z, 0.f); oA.w = fmaxf(oA.w, 0.f);
        oB.x = fmaxf(oB.x, 0.f); oB.y = fmaxf(oB.y, 0.f);
        oB.z = fmaxf(oB.z, 0.f); oB.w = fmaxf(oB.w, 0.f);
    }
    if (lane < 16) {
        ((float4*)out)[(size_t)node * 32 + qlane * 2] = oA;
        ((float4*)out)[(size_t)node * 32 + qlane * 2 + 1] = oB;
    }
}

// ---------------------------------------------------------------------------

extern "C" void kernel_launch(void* const* d_in, const int* in_sizes, int n_in,
                              void* d_out, int out_size, void* d_ws, size_t ws_size,
                              hipStream_t stream) {
    const float* x    = (const float*)d_in[0];
    const int* eidx   = (const int*)d_in[1];
    const float* Wl1  = (const float*)d_in[2];
    const float* bl1  = (const float*)d_in[3];
    const float* Wr1  = (const float*)d_in[4];
    const float* br1  = (const float*)d_in[5];
    const float* att1 = (const float*)d_in[6];
    const float* b1   = (const float*)d_in[7];
    const float* Wl2  = (const float*)d_in[8];
    const float* bl2  = (const float*)d_in[9];
    const float* Wr2  = (const float*)d_in[10];
    const float* br2  = (const float*)d_in[11];
    const float* att2 = (const float*)d_in[12];
    const float* b2   = (const float*)d_in[13];

    const int N = in_sizes[0] / 128;
    const int E = in_sizes[1] / 2;
    const int* src = eidx;
    const int* dst = eidx + E;

    const int nBlk = (N + 255) / 256;

    // workspace layout
    size_t NF = (size_t)N * 128;
    short* xl16 = (short*)d_ws;               // bf16 xl plane [N][128]
    float* bufB = (float*)(xl16 + NF);        // xr fp32
    float* bufC = bufB + NF;                  // h fp32 (layer-1 out)
    int* deg8      = (int*)(bufC + NF);       // [8][N]
    int* dtot      = deg8 + 8 * (size_t)N;    // [N]
    int* row_ptr   = dtot + N;                // [N+1]
    int* blockSums = row_ptr + (N + 1);       // [nBlk]
    int* rpb       = blockSums + nBlk;        // [8][N]
    unsigned short* base8  = (unsigned short*)(rpb + 8 * (size_t)N);  // [8][N]
    unsigned short* rank16 = base8 + 8 * (size_t)N;                   // [E]
    unsigned short* csr16  = rank16 + E;      // [E]
    short* wt      = (short*)(csr16 + E);     // 4 matrices x (hi+lo) x 16384

    float* outF = (float*)d_out;

    const int nCnt = (E + 255) / 256;
    const int gemmBlocks = (N + 31) / 32;
    dim3 aggGrid((N + 3) / 4);

    // 1. W prep + deg8 zero
    prep_zero_kernel<<<32, 256, 0, stream>>>(Wl1, Wr1, Wl2, Wr2, wt, deg8, 8 * N);
    // 2. GEMM layer 1 || degree count (independent -> one grid)
    gemm1_count_kernel<<<gemmBlocks + nCnt, 256, 0, stream>>>(
        x, wt, bl1, xl16, br1, bufB, N, gemmBlocks, dst, deg8, rank16, E, N);
    // 3-5. CSR finish
    scan_blocksum2_kernel<<<nBlk, 256, 0, stream>>>(deg8, base8, dtot, blockSums, N);
    scan_apply2_kernel<<<nBlk, 256, 0, stream>>>(dtot, blockSums, base8, row_ptr, rpb, N, nBlk);
    scatter_edges_kernel<<<nCnt, 256, 0, stream>>>(src, dst, rpb, rank16, csr16, E, N);
    // 6. layer-1 aggregate
    gat_aggregate_kernel<<<aggGrid, 256, 0, stream>>>(xl16, bufB, att1, b1, row_ptr, csr16,
                                                      bufC, N, 1);
    // 7-8. layer 2
    gemm_mfma_dual32_kernel<<<gemmBlocks, 256, 0, stream>>>(bufC, wt + 2 * 2 * 16384, bl2, xl16,
                                                            br2, bufB, N);
    gat_aggregate_kernel<<<aggGrid, 256, 0, stream>>>(xl16, bufB, att2, b2, row_ptr, csr16,
                                                      outF, N, 0);
}

// Round 13
// 286.310 us; speedup vs baseline: 1.0546x; 1.0281x over previous
//
#include <hip/hip_runtime.h>
#include <math.h>

// ---------------------------------------------------------------------------
// GATv2 2-layer GNN, fp32 in/out. N=50000, E=800000, F=128.
// 8 dispatches: prep_zero (W split + zero deg8) -> [GEMM1 ||| count]
//   (INTERLEAVED grid fusion: role = bx%3, 1 GEMM : 2 count -> co-residency;
//   r12's concatenated fusion serialized: 85us = 46+40) -> scan_blocksum2 ->
//   scan_apply2 -> scatter (atomic-free, u16 csr) -> agg1 -> GEMM2 -> agg2
// r13 GEMM epilogue: LDS-staged coalesced writes (r12 counters: 45MB of
//   32/64B scattered stores at ~1TB/s effective was the GEMM's 4x-over-ideal
//   time; now full 128B lines via float4/bf16x8 rows).
// r8: xl bf16 RNE. r9: atomic-free u16 scatter. r11: 8-slice count.
// slice = (edge>>8)&7 in BOTH count and scatter (must match).
// Falsified: grid.sync fusion (r5), split-operand GEMM (r4), agg SW-pipeline
//   (r1/r2), 1-block scan (r6), GEMM tile size (r9/r10), concat fusion (r12).
// ---------------------------------------------------------------------------

typedef short bf16x8 __attribute__((ext_vector_type(8)));
typedef float f32x4 __attribute__((ext_vector_type(4)));

#define LDK 136
#define SMEM_BYTES (2 * 32 * LDK * 2)   // 17408 B staging; epilogue reuses it

// ---------------------------------------------------------------------------
// prep_zero: 32 blocks. Splits the 4 W matrices into bf16 hi/lo [n][k]
// planes AND zeroes deg8 (replaces the memset dispatch).
// ---------------------------------------------------------------------------
__global__ __launch_bounds__(256) void prep_zero_kernel(
    const float* __restrict__ W0, const float* __restrict__ W1,
    const float* __restrict__ W2, const float* __restrict__ W3,
    short* __restrict__ wt, int* __restrict__ deg8, int total8N) {
    int b = blockIdx.x;                  // 0..31
    for (int j = b * 256 + threadIdx.x; j < total8N; j += 32 * 256) deg8[j] = 0;
    int mat = b >> 3, chunk = b & 7;
    const float* W = (mat == 0) ? W0 : (mat == 1) ? W1 : (mat == 2) ? W2 : W3;
    short* hi = wt + (size_t)mat * 2 * 16384;
    short* lo = hi + 16384;
    int i0 = chunk * 2048;
    for (int i = i0 + threadIdx.x; i < i0 + 2048; i += 256) {
        int k = i >> 7, n = i & 127;
        float x = W[i];
        unsigned u = __float_as_uint(x);
        unsigned hu = u & 0xFFFF0000u;
        float lf = x - __uint_as_float(hu);
        hi[n * 128 + k] = (short)(hu >> 16);
        lo[n * 128 + k] = (short)(__float_as_uint(lf) >> 16);
    }
}

// ---------------------------------------------------------------------------
// One-barrier split-bf16 MFMA GEMM body, dual-output 32x256 tile:
//   xl-plane (p=0) -> bf16 RNE [Nrows][128]; xr-plane (p=1) -> fp32.
// Epilogue: D staged in LDS (reusing staging buffer), then written as full
// coalesced rows (float4 / bf16x8) -- r12 showed scattered 32/64B stores
// were the GEMM's dominant cost.
// ---------------------------------------------------------------------------
__device__ __forceinline__ void gemm_dual32_body(
    int bx, const float* __restrict__ X, const short* __restrict__ wtL,
    const float* __restrict__ b0, short* __restrict__ out0bf,
    const float* __restrict__ b1, float* __restrict__ out1,
    int Nrows, char* smem) {
    short (*Ahi)[LDK] = (short (*)[LDK])smem;
    short (*Alo)[LDK] = (short (*)[LDK])(smem + 32 * LDK * 2);

    int tid = threadIdx.x;
    int w = tid >> 6, lane = tid & 63, q = lane >> 4, tr = lane & 15;
    int m0 = bx * 32;
    int n0 = w * 32;

    // B frags for chunk 0, issued before staging/barrier (L2 overlap)
    bf16x8 bh[4], bl[4];
    #pragma unroll
    for (int p = 0; p < 2; ++p) {
        const short* base = wtL + (size_t)p * 2 * 16384;
        #pragma unroll
        for (int nt = 0; nt < 2; ++nt) {
            size_t boff = (size_t)(n0 + nt * 16 + tr) * 128 + q * 8;
            bh[p * 2 + nt] = *(const bf16x8*)&base[boff];
            bl[p * 2 + nt] = *(const bf16x8*)&base[16384 + boff];
        }
    }

    // phase 1: stage 32x128 A-tile, 16 floats per thread
    {
        int srow = tid >> 3;            // 0..31
        int c0 = (tid & 7) * 16;        // 0,16,...,112
        int gr = m0 + srow; if (gr >= Nrows) gr = Nrows - 1;
        const float* xp = &X[(size_t)gr * 128 + c0];
        float4 v[4];
        #pragma unroll
        for (int j = 0; j < 4; ++j) v[j] = *(const float4*)(xp + j * 4);
        #pragma unroll
        for (int j = 0; j < 2; ++j) {
            bf16x8 hv, lv;
            #pragma unroll
            for (int k = 0; k < 2; ++k) {
                float4 vv = v[j * 2 + k];
                float f[4] = {vv.x, vv.y, vv.z, vv.w};
                #pragma unroll
                for (int e = 0; e < 4; ++e) {
                    unsigned u = __float_as_uint(f[e]);
                    unsigned hu = u & 0xFFFF0000u;
                    float lf = f[e] - __uint_as_float(hu);
                    hv[k * 4 + e] = (short)(hu >> 16);
                    lv[k * 4 + e] = (short)(__float_as_uint(lf) >> 16);
                }
            }
            *(bf16x8*)&Ahi[srow][c0 + j * 8] = hv;
            *(bf16x8*)&Alo[srow][c0 + j * 8] = lv;
        }
    }
    __syncthreads();

    // phase 2: pure compute
    f32x4 acc[2][4];   // [mt][p*2+nt]
    #pragma unroll
    for (int a = 0; a < 2; ++a)
        #pragma unroll
        for (int b = 0; b < 4; ++b) acc[a][b] = (f32x4){0.f, 0.f, 0.f, 0.f};

    for (int kc = 0; kc < 128; kc += 32) {
        #pragma unroll
        for (int mt = 0; mt < 2; ++mt) {
            bf16x8 ah = *(const bf16x8*)&Ahi[mt * 16 + tr][kc + q * 8];
            bf16x8 al = *(const bf16x8*)&Alo[mt * 16 + tr][kc + q * 8];
            #pragma unroll
            for (int j = 0; j < 4; ++j) {
                acc[mt][j] = __builtin_amdgcn_mfma_f32_16x16x32_bf16(ah, bh[j], acc[mt][j], 0, 0, 0);
                acc[mt][j] = __builtin_amdgcn_mfma_f32_16x16x32_bf16(ah, bl[j], acc[mt][j], 0, 0, 0);
                acc[mt][j] = __builtin_amdgcn_mfma_f32_16x16x32_bf16(al, bh[j], acc[mt][j], 0, 0, 0);
            }
        }
        if (kc < 96) {
            #pragma unroll
            for (int p = 0; p < 2; ++p) {
                const short* base = wtL + (size_t)p * 2 * 16384;
                #pragma unroll
                for (int nt = 0; nt < 2; ++nt) {
                    size_t boff = (size_t)(n0 + nt * 16 + tr) * 128 + (kc + 32) + q * 8;
                    bh[p * 2 + nt] = *(const bf16x8*)&base[boff];
                    bl[p * 2 + nt] = *(const bf16x8*)&base[16384 + boff];
                }
            }
        }
    }

    // --- epilogue: LDS-staged coalesced writes ---
    int orow = tid >> 3;             // 0..31
    int oc0 = (tid & 7) * 16;        // 0..112
    int gr = m0 + orow;

    // xr plane (fp32), padded rows [32][132] to break 4-way q-bank aliasing
    float (*Ofp)[132] = (float (*)[132])smem;
    __syncthreads();                 // staging reads done
    #pragma unroll
    for (int nt = 0; nt < 2; ++nt) {
        float bv1 = b1[n0 + nt * 16 + tr];
        #pragma unroll
        for (int mt = 0; mt < 2; ++mt)
            #pragma unroll
            for (int r = 0; r < 4; ++r)
                Ofp[mt * 16 + q * 4 + r][n0 + nt * 16 + tr] = acc[mt][2 + nt][r] + bv1;
    }
    __syncthreads();
    if (gr < Nrows) {
        #pragma unroll
        for (int j = 0; j < 4; ++j)
            *(float4*)&out1[(size_t)gr * 128 + oc0 + j * 4] = *(float4*)&Ofp[orow][oc0 + j * 4];
    }
    __syncthreads();

    // xl plane (bf16 RNE), padded rows [32][136]
    short (*Obf)[136] = (short (*)[136])smem;
    #pragma unroll
    for (int nt = 0; nt < 2; ++nt) {
        float bv0 = b0[n0 + nt * 16 + tr];
        #pragma unroll
        for (int mt = 0; mt < 2; ++mt)
            #pragma unroll
            for (int r = 0; r < 4; ++r) {
                float v0 = acc[mt][nt][r] + bv0;
                unsigned u = __float_as_uint(v0);
                unsigned rb = (u + 0x7FFFu + ((u >> 16) & 1u)) >> 16;
                Obf[mt * 16 + q * 4 + r][n0 + nt * 16 + tr] = (short)rb;
            }
    }
    __syncthreads();
    if (gr < Nrows) {
        *(bf16x8*)&out0bf[(size_t)gr * 128 + oc0]     = *(bf16x8*)&Obf[orow][oc0];
        *(bf16x8*)&out0bf[(size_t)gr * 128 + oc0 + 8] = *(bf16x8*)&Obf[orow][oc0 + 8];
    }
}

// --- standalone GEMM (layer 2) ---
__global__ __launch_bounds__(256) void gemm_mfma_dual32_kernel(
    const float* __restrict__ X, const short* __restrict__ wtL,
    const float* __restrict__ b0, short* __restrict__ out0bf,
    const float* __restrict__ b1, float* __restrict__ out1, int Nrows) {
    __shared__ __attribute__((aligned(16))) char smem[SMEM_BYTES];
    gemm_dual32_body(blockIdx.x, X, wtL, b0, out0bf, b1, out1, Nrows, smem);
}

// --- fused, INTERLEAVED: role = bx%3 (0 -> GEMM block bx/3; 1,2 -> count
//     block bx/3*2+(role-1)). GEMM and count waves co-reside on every CU. ---
__global__ __launch_bounds__(256) void gemm1_count_kernel(
    const float* __restrict__ X, const short* __restrict__ wtL,
    const float* __restrict__ b0, short* __restrict__ out0bf,
    const float* __restrict__ b1, float* __restrict__ out1,
    int Nrows, int gemmBlocks,
    const int* __restrict__ dst, int* __restrict__ deg8,
    unsigned short* __restrict__ rank16, int E, int N) {
    __shared__ __attribute__((aligned(16))) char smem[SMEM_BYTES];
    int bx = blockIdx.x;
    int base3 = 3 * gemmBlocks;
    int cb;
    if (bx < base3) {
        int role = bx % 3, g = bx / 3;
        if (role == 0) {
            gemm_dual32_body(g, X, wtL, b0, out0bf, b1, out1, Nrows, smem);
            return;
        }
        cb = g * 2 + (role - 1);
    } else {
        cb = 2 * gemmBlocks + (bx - base3);   // tail count blocks (if any)
    }
    int i = cb * 256 + threadIdx.x;
    if (i < E) {
        int slice = (i >> 8) & 7;            // must match scatter
        int r = atomicAdd(&deg8[(size_t)slice * N + dst[i]], 1);
        rank16[i] = (unsigned short)r;
    }
}

// --- scan pass 1: per-node slice prefix (base8, u16), per-node total (dtot),
//     per-256-node block sums ---
__global__ __launch_bounds__(256) void scan_blocksum2_kernel(
    const int* __restrict__ deg8, unsigned short* __restrict__ base8,
    int* __restrict__ dtot, int* __restrict__ blockSums, int n) {
    __shared__ int wsum[4];
    int tid = threadIdx.x;
    int idx = blockIdx.x * 256 + tid;
    int lane = tid & 63, wid = tid >> 6;
    int tot = 0;
    if (idx < n) {
        int b = 0;
        #pragma unroll
        for (int s = 0; s < 8; ++s) {
            int v = deg8[(size_t)s * n + idx];
            base8[(size_t)s * n + idx] = (unsigned short)b;
            b += v;
        }
        tot = b;
        dtot[idx] = tot;
    }
    int v = tot;
    #pragma unroll
    for (int off = 32; off > 0; off >>= 1) v += __shfl_xor(v, off);
    if (lane == 0) wsum[wid] = v;
    __syncthreads();
    if (tid == 0) blockSums[blockIdx.x] = wsum[0] + wsum[1] + wsum[2] + wsum[3];
}

// --- scan pass 2 (fused): block offset by direct reduction over blockSums
//     (nBlk <= 256) + local scan -> row_ptr, rpb[s][n] = excl + base8[s][n].
__global__ __launch_bounds__(256) void scan_apply2_kernel(
    const int* __restrict__ dtot, const int* __restrict__ blockSums,
    const unsigned short* __restrict__ base8,
    int* __restrict__ row_ptr, int* __restrict__ rpb, int n, int nBlk) {
    __shared__ int sPre[4], sAll[4], wsum[4];
    int tid = threadIdx.x, lane = tid & 63, wid = tid >> 6;

    int bsv = (tid < nBlk) ? blockSums[tid] : 0;
    int pre = (tid < (int)blockIdx.x) ? bsv : 0;
    int all = bsv;
    #pragma unroll
    for (int off = 32; off > 0; off >>= 1) {
        pre += __shfl_xor(pre, off);
        all += __shfl_xor(all, off);
    }
    if (lane == 0) { sPre[wid] = pre; sAll[wid] = all; }
    __syncthreads();
    int off0 = sPre[0] + sPre[1] + sPre[2] + sPre[3];
    int total = sAll[0] + sAll[1] + sAll[2] + sAll[3];

    int idx = blockIdx.x * 256 + tid;
    int v = (idx < n) ? dtot[idx] : 0;
    int incl = v;
    #pragma unroll
    for (int off = 1; off < 64; off <<= 1) {
        int t = __shfl_up(incl, off);
        if (lane >= off) incl += t;
    }
    if (lane == 63) wsum[wid] = incl;
    __syncthreads();
    int woff = 0;
    #pragma unroll
    for (int w = 0; w < 4; ++w) woff += (w < wid) ? wsum[w] : 0;
    int excl = off0 + woff + (incl - v);
    if (idx < n) {
        row_ptr[idx] = excl;
        #pragma unroll
        for (int s = 0; s < 8; ++s)
            rpb[(size_t)s * n + idx] = excl + (int)base8[(size_t)s * n + idx];
    }
    if (blockIdx.x == 0 && tid == 0) row_ptr[n] = total;
}

// --- atomic-free scatter: slice = (i>>8)&7 (matches count);
//     pos = rpb[slice][dst] + rank16, csr entry = u16 src ---
__global__ void scatter_edges_kernel(const int* __restrict__ src, const int* __restrict__ dst,
                                     const int* __restrict__ rpb,
                                     const unsigned short* __restrict__ rank16,
                                     unsigned short* __restrict__ csr16, int E, int N) {
    int i = blockIdx.x * blockDim.x + threadIdx.x;
    if (i < E) {
        int d = dst[i];
        int slice = (i >> 8) & 7;
        int pos = rpb[(size_t)slice * N + d] + (int)rank16[i];
        csr16[pos] = (unsigned short)src[i];
    }
}

// ---------------------------------------------------------------------------
// Aggregation v6: xl is bf16 [N][128], csr entries u16. 16-lane groups,
// 4 edges/wave. Lane qlane holds features [qlane*8, qlane*8+8): ONE 16B load
// per edge-row. leaky = fmaxf(t, 0.2t). Per-edge reduce: 4 intra-16 shfl_xor.
// ---------------------------------------------------------------------------
__global__ __launch_bounds__(256) void gat_aggregate_kernel(
    const short* __restrict__ xl16, const float* __restrict__ xr,
    const float* __restrict__ att, const float* __restrict__ bias,
    const int* __restrict__ row_ptr, const unsigned short* __restrict__ csr16,
    float* __restrict__ out, int N, int applyRelu) {
    int wid = threadIdx.x >> 6;      // 0..3 -> node within block
    int lane = threadIdx.x & 63;
    int qlane = lane & 15;
    int qid = lane >> 4;
    int node = blockIdx.x * 4 + wid;
    if (node >= N) return;

    const bf16x8* xlb = (const bf16x8*)xl16;   // row = 16 x bf16x8
    float4 xrA = ((const float4*)xr)[(size_t)node * 32 + qlane * 2];
    float4 xrB = ((const float4*)xr)[(size_t)node * 32 + qlane * 2 + 1];
    float4 atA = ((const float4*)att)[qlane * 2];
    float4 atB = ((const float4*)att)[qlane * 2 + 1];

    int beg = row_ptr[node];
    int end = row_ptr[node + 1];

    float dsum = 0.f;
    float4 accA = {0.f, 0.f, 0.f, 0.f};
    float4 accB = {0.f, 0.f, 0.f, 0.f};

    for (int cbase = beg; cbase < end; cbase += 64) {
        int cnt = end - cbase;
        if (cnt > 64) cnt = 64;
        int myidx = (lane < cnt) ? (int)csr16[cbase + lane] : 0;  // coalesced u16
        int nq = (cnt + 3) >> 2;                                  // quads of 4 edges

        for (int g = 0; g < nq; ++g) {
            int eidx = 4 * g + qid;
            int s = __shfl(myidx, eidx);
            bf16x8 mv = xlb[((size_t)s << 4) + qlane];
            float4 vA, vB;
            vA.x = __uint_as_float(((unsigned)(unsigned short)mv[0]) << 16);
            vA.y = __uint_as_float(((unsigned)(unsigned short)mv[1]) << 16);
            vA.z = __uint_as_float(((unsigned)(unsigned short)mv[2]) << 16);
            vA.w = __uint_as_float(((unsigned)(unsigned short)mv[3]) << 16);
            vB.x = __uint_as_float(((unsigned)(unsigned short)mv[4]) << 16);
            vB.y = __uint_as_float(((unsigned)(unsigned short)mv[5]) << 16);
            vB.z = __uint_as_float(((unsigned)(unsigned short)mv[6]) << 16);
            vB.w = __uint_as_float(((unsigned)(unsigned short)mv[7]) << 16);

            float t, p;
            t = vA.x + xrA.x; t = fmaxf(t, 0.2f * t); p = t * atA.x;
            t = vA.y + xrA.y; t = fmaxf(t, 0.2f * t); p = fmaf(t, atA.y, p);
            t = vA.z + xrA.z; t = fmaxf(t, 0.2f * t); p = fmaf(t, atA.z, p);
            t = vA.w + xrA.w; t = fmaxf(t, 0.2f * t); p = fmaf(t, atA.w, p);
            t = vB.x + xrB.x; t = fmaxf(t, 0.2f * t); p = fmaf(t, atB.x, p);
            t = vB.y + xrB.y; t = fmaxf(t, 0.2f * t); p = fmaf(t, atB.y, p);
            t = vB.z + xrB.z; t = fmaxf(t, 0.2f * t); p = fmaf(t, atB.z, p);
            t = vB.w + xrB.w; t = fmaxf(t, 0.2f * t); p = fmaf(t, atB.w, p);

            p += __shfl_xor(p, 1);
            p += __shfl_xor(p, 2);
            p += __shfl_xor(p, 4);
            p += __shfl_xor(p, 8);

            float e = (eidx < cnt) ? __expf(p) : 0.f;
            dsum += e;
            accA.x = fmaf(e, vA.x, accA.x);
            accA.y = fmaf(e, vA.y, accA.y);
            accA.z = fmaf(e, vA.z, accA.z);
            accA.w = fmaf(e, vA.w, accA.w);
            accB.x = fmaf(e, vB.x, accB.x);
            accB.y = fmaf(e, vB.y, accB.y);
            accB.z = fmaf(e, vB.z, accB.z);
            accB.w = fmaf(e, vB.w, accB.w);
        }
    }

    #pragma unroll
    for (int off = 16; off <= 32; off <<= 1) {
        dsum += __shfl_xor(dsum, off);
        accA.x += __shfl_xor(accA.x, off);
        accA.y += __shfl_xor(accA.y, off);
        accA.z += __shfl_xor(accA.z, off);
        accA.w += __shfl_xor(accA.w, off);
        accB.x += __shfl_xor(accB.x, off);
        accB.y += __shfl_xor(accB.y, off);
        accB.z += __shfl_xor(accB.z, off);
        accB.w += __shfl_xor(accB.w, off);
    }

    float inv = dsum > 0.f ? 1.f / dsum : 0.f;
    float4 bvA = ((const float4*)bias)[qlane * 2];
    float4 bvB = ((const float4*)bias)[qlane * 2 + 1];
    float4 oA, oB;
    oA.x = accA.x * inv + bvA.x; oA.y = accA.y * inv + bvA.y;
    oA.z = accA.z * inv + bvA.z; oA.w = accA.w * inv + bvA.w;
    oB.x = accB.x * inv + bvB.x; oB.y = accB.y * inv + bvB.y;
    oB.z = accB.z * inv + bvB.z; oB.w = accB.w * inv + bvB.w;
    if (applyRelu) {
        oA.x = fmaxf(oA.x, 0.f); oA.y = fmaxf(oA.y, 0.f);
        oA.z = fmaxf(oA.z, 0.f); oA.w = fmaxf(oA.w, 0.f);
        oB.x = fmaxf(oB.x, 0.f); oB.y = fmaxf(oB.y, 0.f);
        oB.z = fmaxf(oB.z, 0.f); oB.w = fmaxf(oB.w, 0.f);
    }
    if (lane < 16) {
        ((float4*)out)[(size_t)node * 32 + qlane * 2] = oA;
        ((float4*)out)[(size_t)node * 32 + qlane * 2 + 1] = oB;
    }
}

// ---------------------------------------------------------------------------

extern "C" void kernel_launch(void* const* d_in, const int* in_sizes, int n_in,
                              void* d_out, int out_size, void* d_ws, size_t ws_size,
                              hipStream_t stream) {
    const float* x    = (const float*)d_in[0];
    const int* eidx   = (const int*)d_in[1];
    const float* Wl1  = (const float*)d_in[2];
    const float* bl1  = (const float*)d_in[3];
    const float* Wr1  = (const float*)d_in[4];
    const float* br1  = (const float*)d_in[5];
    const float* att1 = (const float*)d_in[6];
    const float* b1   = (const float*)d_in[7];
    const float* Wl2  = (const float*)d_in[8];
    const float* bl2  = (const float*)d_in[9];
    const float* Wr2  = (const float*)d_in[10];
    const float* br2  = (const float*)d_in[11];
    const float* att2 = (const float*)d_in[12];
    const float* b2   = (const float*)d_in[13];

    const int N = in_sizes[0] / 128;
    const int E = in_sizes[1] / 2;
    const int* src = eidx;
    const int* dst = eidx + E;

    const int nBlk = (N + 255) / 256;

    // workspace layout
    size_t NF = (size_t)N * 128;
    short* xl16 = (short*)d_ws;               // bf16 xl plane [N][128]
    float* bufB = (float*)(xl16 + NF);        // xr fp32
    float* bufC = bufB + NF;                  // h fp32 (layer-1 out)
    int* deg8      = (int*)(bufC + NF);       // [8][N]
    int* dtot      = deg8 + 8 * (size_t)N;    // [N]
    int* row_ptr   = dtot + N;                // [N+1]
    int* blockSums = row_ptr + (N + 1);       // [nBlk]
    int* rpb       = blockSums + nBlk;        // [8][N]
    unsigned short* base8  = (unsigned short*)(rpb + 8 * (size_t)N);  // [8][N]
    unsigned short* rank16 = base8 + 8 * (size_t)N;                   // [E]
    unsigned short* csr16  = rank16 + E;      // [E]
    short* wt      = (short*)(csr16 + E);     // 4 matrices x (hi+lo) x 16384

    float* outF = (float*)d_out;

    const int nCnt = (E + 255) / 256;
    const int gemmBlocks = (N + 31) / 32;
    int fusedGrid = 3 * gemmBlocks;
    if (nCnt > 2 * gemmBlocks) fusedGrid += nCnt - 2 * gemmBlocks;
    dim3 aggGrid((N + 3) / 4);

    // 1. W prep + deg8 zero
    prep_zero_kernel<<<32, 256, 0, stream>>>(Wl1, Wr1, Wl2, Wr2, wt, deg8, 8 * N);
    // 2. GEMM layer 1 ||| degree count (interleaved roles, co-resident)
    gemm1_count_kernel<<<fusedGrid, 256, 0, stream>>>(
        x, wt, bl1, xl16, br1, bufB, N, gemmBlocks, dst, deg8, rank16, E, N);
    // 3-5. CSR finish
    scan_blocksum2_kernel<<<nBlk, 256, 0, stream>>>(deg8, base8, dtot, blockSums, N);
    scan_apply2_kernel<<<nBlk, 256, 0, stream>>>(dtot, blockSums, base8, row_ptr, rpb, N, nBlk);
    scatter_edges_kernel<<<nCnt, 256, 0, stream>>>(src, dst, rpb, rank16, csr16, E, N);
    // 6. layer-1 aggregate
    gat_aggregate_kernel<<<aggGrid, 256, 0, stream>>>(xl16, bufB, att1, b1, row_ptr, csr16,
                                                      bufC, N, 1);
    // 7-8. layer 2
    gemm_mfma_dual32_kernel<<<gemmBlocks, 256, 0, stream>>>(bufC, wt + 2 * 2 * 16384, bl2, xl16,
                                                            br2, bufB, N);
    gat_aggregate_kernel<<<aggGrid, 256, 0, stream>>>(xl16, bufB, att2, b2, row_ptr, csr16,
                                                      outF, N, 0);
}

// Round 14
// 284.524 us; speedup vs baseline: 1.0612x; 1.0063x over previous
//
#include <hip/hip_runtime.h>
#include <math.h>

// ---------------------------------------------------------------------------
// GATv2 2-layer GNN, fp32 in/out. N=50000, E=800000, F=128.
// 7 dispatches: prep_zero (W split + zero deg8+pub) -> [GEMM1 ||| count]
//   (interleaved roles 1:2) -> scan_fused (single-pass: publish + lookback;
//   196 blocks co-resident, publish-before-spin => deadlock-free) ->
//   scatter (atomic-free, u16 csr) -> agg1 -> GEMM2 -> agg2
// r8: xl bf16 RNE. r9: atomic-free u16 scatter. r11: 8-slice count.
// r13: coalesced GEMM epilogue + interleaved fusion. r14: single-pass scan
//   (base8/dtot stay in registers), packed bf16 extraction in agg.
// slice = (edge>>8)&7 in BOTH count and scatter (must match).
// Falsified: grid.sync fusion (r5), split-operand GEMM (r4), agg SW-pipeline
//   (r1/r2), 1-block scan (r6), GEMM tile size (r9/r10), concat fusion (r12).
// ---------------------------------------------------------------------------

typedef short bf16x8 __attribute__((ext_vector_type(8)));
typedef float f32x4 __attribute__((ext_vector_type(4)));

#define LDK 136
#define SMEM_BYTES (2 * 32 * LDK * 2)   // 17408 B staging; epilogue reuses it

// ---------------------------------------------------------------------------
// prep_zero: 32 blocks. Splits the 4 W matrices into bf16 hi/lo [n][k]
// planes AND zeroes deg8+pub (contiguous; replaces the memset dispatch).
// ---------------------------------------------------------------------------
__global__ __launch_bounds__(256) void prep_zero_kernel(
    const float* __restrict__ W0, const float* __restrict__ W1,
    const float* __restrict__ W2, const float* __restrict__ W3,
    short* __restrict__ wt, int* __restrict__ zbase, int ztotal) {
    int b = blockIdx.x;                  // 0..31
    for (int j = b * 256 + threadIdx.x; j < ztotal; j += 32 * 256) zbase[j] = 0;
    int mat = b >> 3, chunk = b & 7;
    const float* W = (mat == 0) ? W0 : (mat == 1) ? W1 : (mat == 2) ? W2 : W3;
    short* hi = wt + (size_t)mat * 2 * 16384;
    short* lo = hi + 16384;
    int i0 = chunk * 2048;
    for (int i = i0 + threadIdx.x; i < i0 + 2048; i += 256) {
        int k = i >> 7, n = i & 127;
        float x = W[i];
        unsigned u = __float_as_uint(x);
        unsigned hu = u & 0xFFFF0000u;
        float lf = x - __uint_as_float(hu);
        hi[n * 128 + k] = (short)(hu >> 16);
        lo[n * 128 + k] = (short)(__float_as_uint(lf) >> 16);
    }
}

// ---------------------------------------------------------------------------
// One-barrier split-bf16 MFMA GEMM body, dual-output 32x256 tile:
//   xl-plane (p=0) -> bf16 RNE [Nrows][128]; xr-plane (p=1) -> fp32.
// Epilogue: LDS-staged coalesced writes (r13).
// ---------------------------------------------------------------------------
__device__ __forceinline__ void gemm_dual32_body(
    int bx, const float* __restrict__ X, const short* __restrict__ wtL,
    const float* __restrict__ b0, short* __restrict__ out0bf,
    const float* __restrict__ b1, float* __restrict__ out1,
    int Nrows, char* smem) {
    short (*Ahi)[LDK] = (short (*)[LDK])smem;
    short (*Alo)[LDK] = (short (*)[LDK])(smem + 32 * LDK * 2);

    int tid = threadIdx.x;
    int w = tid >> 6, lane = tid & 63, q = lane >> 4, tr = lane & 15;
    int m0 = bx * 32;
    int n0 = w * 32;

    // B frags for chunk 0, issued before staging/barrier (L2 overlap)
    bf16x8 bh[4], bl[4];
    #pragma unroll
    for (int p = 0; p < 2; ++p) {
        const short* base = wtL + (size_t)p * 2 * 16384;
        #pragma unroll
        for (int nt = 0; nt < 2; ++nt) {
            size_t boff = (size_t)(n0 + nt * 16 + tr) * 128 + q * 8;
            bh[p * 2 + nt] = *(const bf16x8*)&base[boff];
            bl[p * 2 + nt] = *(const bf16x8*)&base[16384 + boff];
        }
    }

    // phase 1: stage 32x128 A-tile, 16 floats per thread
    {
        int srow = tid >> 3;            // 0..31
        int c0 = (tid & 7) * 16;        // 0,16,...,112
        int gr = m0 + srow; if (gr >= Nrows) gr = Nrows - 1;
        const float* xp = &X[(size_t)gr * 128 + c0];
        float4 v[4];
        #pragma unroll
        for (int j = 0; j < 4; ++j) v[j] = *(const float4*)(xp + j * 4);
        #pragma unroll
        for (int j = 0; j < 2; ++j) {
            bf16x8 hv, lv;
            #pragma unroll
            for (int k = 0; k < 2; ++k) {
                float4 vv = v[j * 2 + k];
                float f[4] = {vv.x, vv.y, vv.z, vv.w};
                #pragma unroll
                for (int e = 0; e < 4; ++e) {
                    unsigned u = __float_as_uint(f[e]);
                    unsigned hu = u & 0xFFFF0000u;
                    float lf = f[e] - __uint_as_float(hu);
                    hv[k * 4 + e] = (short)(hu >> 16);
                    lv[k * 4 + e] = (short)(__float_as_uint(lf) >> 16);
                }
            }
            *(bf16x8*)&Ahi[srow][c0 + j * 8] = hv;
            *(bf16x8*)&Alo[srow][c0 + j * 8] = lv;
        }
    }
    __syncthreads();

    // phase 2: pure compute
    f32x4 acc[2][4];   // [mt][p*2+nt]
    #pragma unroll
    for (int a = 0; a < 2; ++a)
        #pragma unroll
        for (int b = 0; b < 4; ++b) acc[a][b] = (f32x4){0.f, 0.f, 0.f, 0.f};

    for (int kc = 0; kc < 128; kc += 32) {
        #pragma unroll
        for (int mt = 0; mt < 2; ++mt) {
            bf16x8 ah = *(const bf16x8*)&Ahi[mt * 16 + tr][kc + q * 8];
            bf16x8 al = *(const bf16x8*)&Alo[mt * 16 + tr][kc + q * 8];
            #pragma unroll
            for (int j = 0; j < 4; ++j) {
                acc[mt][j] = __builtin_amdgcn_mfma_f32_16x16x32_bf16(ah, bh[j], acc[mt][j], 0, 0, 0);
                acc[mt][j] = __builtin_amdgcn_mfma_f32_16x16x32_bf16(ah, bl[j], acc[mt][j], 0, 0, 0);
                acc[mt][j] = __builtin_amdgcn_mfma_f32_16x16x32_bf16(al, bh[j], acc[mt][j], 0, 0, 0);
            }
        }
        if (kc < 96) {
            #pragma unroll
            for (int p = 0; p < 2; ++p) {
                const short* base = wtL + (size_t)p * 2 * 16384;
                #pragma unroll
                for (int nt = 0; nt < 2; ++nt) {
                    size_t boff = (size_t)(n0 + nt * 16 + tr) * 128 + (kc + 32) + q * 8;
                    bh[p * 2 + nt] = *(const bf16x8*)&base[boff];
                    bl[p * 2 + nt] = *(const bf16x8*)&base[16384 + boff];
                }
            }
        }
    }

    // --- epilogue: LDS-staged coalesced writes ---
    int orow = tid >> 3;             // 0..31
    int oc0 = (tid & 7) * 16;        // 0..112
    int gr = m0 + orow;

    float (*Ofp)[132] = (float (*)[132])smem;
    __syncthreads();                 // staging reads done
    #pragma unroll
    for (int nt = 0; nt < 2; ++nt) {
        float bv1 = b1[n0 + nt * 16 + tr];
        #pragma unroll
        for (int mt = 0; mt < 2; ++mt)
            #pragma unroll
            for (int r = 0; r < 4; ++r)
                Ofp[mt * 16 + q * 4 + r][n0 + nt * 16 + tr] = acc[mt][2 + nt][r] + bv1;
    }
    __syncthreads();
    if (gr < Nrows) {
        #pragma unroll
        for (int j = 0; j < 4; ++j)
            *(float4*)&out1[(size_t)gr * 128 + oc0 + j * 4] = *(float4*)&Ofp[orow][oc0 + j * 4];
    }
    __syncthreads();

    short (*Obf)[136] = (short (*)[136])smem;
    #pragma unroll
    for (int nt = 0; nt < 2; ++nt) {
        float bv0 = b0[n0 + nt * 16 + tr];
        #pragma unroll
        for (int mt = 0; mt < 2; ++mt)
            #pragma unroll
            for (int r = 0; r < 4; ++r) {
                float v0 = acc[mt][nt][r] + bv0;
                unsigned u = __float_as_uint(v0);
                unsigned rb = (u + 0x7FFFu + ((u >> 16) & 1u)) >> 16;
                Obf[mt * 16 + q * 4 + r][n0 + nt * 16 + tr] = (short)rb;
            }
    }
    __syncthreads();
    if (gr < Nrows) {
        *(bf16x8*)&out0bf[(size_t)gr * 128 + oc0]     = *(bf16x8*)&Obf[orow][oc0];
        *(bf16x8*)&out0bf[(size_t)gr * 128 + oc0 + 8] = *(bf16x8*)&Obf[orow][oc0 + 8];
    }
}

// --- standalone GEMM (layer 2) ---
__global__ __launch_bounds__(256) void gemm_mfma_dual32_kernel(
    const float* __restrict__ X, const short* __restrict__ wtL,
    const float* __restrict__ b0, short* __restrict__ out0bf,
    const float* __restrict__ b1, float* __restrict__ out1, int Nrows) {
    __shared__ __attribute__((aligned(16))) char smem[SMEM_BYTES];
    gemm_dual32_body(blockIdx.x, X, wtL, b0, out0bf, b1, out1, Nrows, smem);
}

// --- fused, INTERLEAVED: role = bx%3 (0 -> GEMM block bx/3; 1,2 -> count
//     block bx/3*2+(role-1)). GEMM and count waves co-reside on every CU. ---
__global__ __launch_bounds__(256) void gemm1_count_kernel(
    const float* __restrict__ X, const short* __restrict__ wtL,
    const float* __restrict__ b0, short* __restrict__ out0bf,
    const float* __restrict__ b1, float* __restrict__ out1,
    int Nrows, int gemmBlocks,
    const int* __restrict__ dst, int* __restrict__ deg8,
    unsigned short* __restrict__ rank16, int E, int N) {
    __shared__ __attribute__((aligned(16))) char smem[SMEM_BYTES];
    int bx = blockIdx.x;
    int base3 = 3 * gemmBlocks;
    int cb;
    if (bx < base3) {
        int role = bx % 3, g = bx / 3;
        if (role == 0) {
            gemm_dual32_body(g, X, wtL, b0, out0bf, b1, out1, Nrows, smem);
            return;
        }
        cb = g * 2 + (role - 1);
    } else {
        cb = 2 * gemmBlocks + (bx - base3);   // tail count blocks (if any)
    }
    int i = cb * 256 + threadIdx.x;
    if (i < E) {
        int slice = (i >> 8) & 7;            // must match scatter
        int r = atomicAdd(&deg8[(size_t)slice * N + dst[i]], 1);
        rank16[i] = (unsigned short)r;
    }
}

// ---------------------------------------------------------------------------
// Single-pass scan (publish + lookback). 196 blocks, all co-resident
// (grid <= 256 CUs); each block PUBLISHES its sum before spinning on
// predecessors, so forward progress is guaranteed. pub[] pre-zeroed;
// published value = bsum+1 (nonzero flag). base8/dtot live in registers.
// Outputs: row_ptr[0..n], rpb[s][node] = row_ptr[node] + slice-prefix.
// ---------------------------------------------------------------------------
__global__ __launch_bounds__(256) void scan_fused_kernel(
    const int* __restrict__ deg8, int* __restrict__ pub,
    int* __restrict__ row_ptr, int* __restrict__ rpb, int n, int nBlk) {
    __shared__ int sA[4], sB[4];
    __shared__ int sBsum;
    int tid = threadIdx.x, lane = tid & 63, wid = tid >> 6;
    int idx = blockIdx.x * 256 + tid;

    int b8[8];
    int tot = 0;
    if (idx < n) {
        #pragma unroll
        for (int s = 0; s < 8; ++s) {
            int v = deg8[(size_t)s * n + idx];
            b8[s] = tot;
            tot += v;
        }
    }

    // block sum of tot -> bsum; publish bsum+1
    int v = tot;
    #pragma unroll
    for (int off = 32; off > 0; off >>= 1) v += __shfl_xor(v, off);
    if (lane == 0) sA[wid] = v;
    __syncthreads();
    if (tid == 0) {
        int bs = sA[0] + sA[1] + sA[2] + sA[3];
        sBsum = bs;
        atomicExch(&pub[blockIdx.x], bs + 1);
    }
    __syncthreads();
    int bsum = sBsum;

    // lookback: thread t (< blockIdx.x) spin-reads pub[t]
    int pv = 0;
    if (tid < (int)blockIdx.x) {
        while ((pv = atomicAdd(&pub[tid], 0)) == 0) {}
        pv -= 1;
    }
    int pr = pv;
    #pragma unroll
    for (int off = 32; off > 0; off >>= 1) pr += __shfl_xor(pr, off);
    if (lane == 0) sB[wid] = pr;
    __syncthreads();
    int off0 = sB[0] + sB[1] + sB[2] + sB[3];

    // local exclusive scan of tot within the block
    int incl = tot;
    #pragma unroll
    for (int off = 1; off < 64; off <<= 1) {
        int t = __shfl_up(incl, off);
        if (lane >= off) incl += t;
    }
    if (lane == 63) sA[wid] = incl;
    __syncthreads();
    int woff = 0;
    #pragma unroll
    for (int w = 0; w < 4; ++w) woff += (w < wid) ? sA[w] : 0;
    int excl = off0 + woff + (incl - tot);
    if (idx < n) {
        row_ptr[idx] = excl;
        #pragma unroll
        for (int s = 0; s < 8; ++s)
            rpb[(size_t)s * n + idx] = excl + b8[s];
    }
    if ((int)blockIdx.x == nBlk - 1 && tid == 0) row_ptr[n] = off0 + bsum;
}

// --- atomic-free scatter: slice = (i>>8)&7 (matches count);
//     pos = rpb[slice][dst] + rank16, csr entry = u16 src ---
__global__ void scatter_edges_kernel(const int* __restrict__ src, const int* __restrict__ dst,
                                     const int* __restrict__ rpb,
                                     const unsigned short* __restrict__ rank16,
                                     unsigned short* __restrict__ csr16, int E, int N) {
    int i = blockIdx.x * blockDim.x + threadIdx.x;
    if (i < E) {
        int d = dst[i];
        int slice = (i >> 8) & 7;
        int pos = rpb[(size_t)slice * N + d] + (int)rank16[i];
        csr16[pos] = (unsigned short)src[i];
    }
}

// ---------------------------------------------------------------------------
// Aggregation v7: xl is bf16 [N][128], csr entries u16. 16-lane groups,
// 4 edges/wave. Packed bf16 extraction: per dword, lo = d<<16,
// hi = d & 0xFFFF0000 (8 ops per edge-row). leaky = fmaxf(t, 0.2t).
// Per-edge reduce: 4 intra-16 shfl_xor (DPP). xor16/32 hoisted per node.
// ---------------------------------------------------------------------------
__global__ __launch_bounds__(256) void gat_aggregate_kernel(
    const short* __restrict__ xl16, const float* __restrict__ xr,
    const float* __restrict__ att, const float* __restrict__ bias,
    const int* __restrict__ row_ptr, const unsigned short* __restrict__ csr16,
    float* __restrict__ out, int N, int applyRelu) {
    int wid = threadIdx.x >> 6;      // 0..3 -> node within block
    int lane = threadIdx.x & 63;
    int qlane = lane & 15;
    int qid = lane >> 4;
    int node = blockIdx.x * 4 + wid;
    if (node >= N) return;

    const uint4* xlb = (const uint4*)xl16;     // row = 16 x uint4
    float4 xrA = ((const float4*)xr)[(size_t)node * 32 + qlane * 2];
    float4 xrB = ((const float4*)xr)[(size_t)node * 32 + qlane * 2 + 1];
    float4 atA = ((const float4*)att)[qlane * 2];
    float4 atB = ((const float4*)att)[qlane * 2 + 1];

    int beg = row_ptr[node];
    int end = row_ptr[node + 1];

    float dsum = 0.f;
    float4 accA = {0.f, 0.f, 0.f, 0.f};
    float4 accB = {0.f, 0.f, 0.f, 0.f};

    for (int cbase = beg; cbase < end; cbase += 64) {
        int cnt = end - cbase;
        if (cnt > 64) cnt = 64;
        int myidx = (lane < cnt) ? (int)csr16[cbase + lane] : 0;  // coalesced u16
        int nq = (cnt + 3) >> 2;                                  // quads of 4 edges

        for (int g = 0; g < nq; ++g) {
            int eidx = 4 * g + qid;
            int s = __shfl(myidx, eidx);
            uint4 md = xlb[((size_t)s << 4) + qlane];
            float4 vA, vB;
            vA.x = __uint_as_float(md.x << 16);
            vA.y = __uint_as_float(md.x & 0xFFFF0000u);
            vA.z = __uint_as_float(md.y << 16);
            vA.w = __uint_as_float(md.y & 0xFFFF0000u);
            vB.x = __uint_as_float(md.z << 16);
            vB.y = __uint_as_float(md.z & 0xFFFF0000u);
            vB.z = __uint_as_float(md.w << 16);
            vB.w = __uint_as_float(md.w & 0xFFFF0000u);

            float t, p;
            t = vA.x + xrA.x; t = fmaxf(t, 0.2f * t); p = t * atA.x;
            t = vA.y + xrA.y; t = fmaxf(t, 0.2f * t); p = fmaf(t, atA.y, p);
            t = vA.z + xrA.z; t = fmaxf(t, 0.2f * t); p = fmaf(t, atA.z, p);
            t = vA.w + xrA.w; t = fmaxf(t, 0.2f * t); p = fmaf(t, atA.w, p);
            t = vB.x + xrB.x; t = fmaxf(t, 0.2f * t); p = fmaf(t, atB.x, p);
            t = vB.y + xrB.y; t = fmaxf(t, 0.2f * t); p = fmaf(t, atB.y, p);
            t = vB.z + xrB.z; t = fmaxf(t, 0.2f * t); p = fmaf(t, atB.z, p);
            t = vB.w + xrB.w; t = fmaxf(t, 0.2f * t); p = fmaf(t, atB.w, p);

            p += __shfl_xor(p, 1);
            p += __shfl_xor(p, 2);
            p += __shfl_xor(p, 4);
            p += __shfl_xor(p, 8);

            float e = (eidx < cnt) ? __expf(p) : 0.f;
            dsum += e;
            accA.x = fmaf(e, vA.x, accA.x);
            accA.y = fmaf(e, vA.y, accA.y);
            accA.z = fmaf(e, vA.z, accA.z);
            accA.w = fmaf(e, vA.w, accA.w);
            accB.x = fmaf(e, vB.x, accB.x);
            accB.y = fmaf(e, vB.y, accB.y);
            accB.z = fmaf(e, vB.z, accB.z);
            accB.w = fmaf(e, vB.w, accB.w);
        }
    }

    #pragma unroll
    for (int off = 16; off <= 32; off <<= 1) {
        dsum += __shfl_xor(dsum, off);
        accA.x += __shfl_xor(accA.x, off);
        accA.y += __shfl_xor(accA.y, off);
        accA.z += __shfl_xor(accA.z, off);
        accA.w += __shfl_xor(accA.w, off);
        accB.x += __shfl_xor(accB.x, off);
        accB.y += __shfl_xor(accB.y, off);
        accB.z += __shfl_xor(accB.z, off);
        accB.w += __shfl_xor(accB.w, off);
    }

    float inv = dsum > 0.f ? 1.f / dsum : 0.f;
    float4 bvA = ((const float4*)bias)[qlane * 2];
    float4 bvB = ((const float4*)bias)[qlane * 2 + 1];
    float4 oA, oB;
    oA.x = accA.x * inv + bvA.x; oA.y = accA.y * inv + bvA.y;
    oA.z = accA.z * inv + bvA.z; oA.w = accA.w * inv + bvA.w;
    oB.x = accB.x * inv + bvB.x; oB.y = accB.y * inv + bvB.y;
    oB.z = accB.z * inv + bvB.z; oB.w = accB.w * inv + bvB.w;
    if (applyRelu) {
        oA.x = fmaxf(oA.x, 0.f); oA.y = fmaxf(oA.y, 0.f);
        oA.z = fmaxf(oA.z, 0.f); oA.w = fmaxf(oA.w, 0.f);
        oB.x = fmaxf(oB.x, 0.f); oB.y = fmaxf(oB.y, 0.f);
        oB.z = fmaxf(oB.z, 0.f); oB.w = fmaxf(oB.w, 0.f);
    }
    if (lane < 16) {
        ((float4*)out)[(size_t)node * 32 + qlane * 2] = oA;
        ((float4*)out)[(size_t)node * 32 + qlane * 2 + 1] = oB;
    }
}

// ---------------------------------------------------------------------------

extern "C" void kernel_launch(void* const* d_in, const int* in_sizes, int n_in,
                              void* d_out, int out_size, void* d_ws, size_t ws_size,
                              hipStream_t stream) {
    const float* x    = (const float*)d_in[0];
    const int* eidx   = (const int*)d_in[1];
    const float* Wl1  = (const float*)d_in[2];
    const float* bl1  = (const float*)d_in[3];
    const float* Wr1  = (const float*)d_in[4];
    const float* br1  = (const float*)d_in[5];
    const float* att1 = (const float*)d_in[6];
    const float* b1   = (const float*)d_in[7];
    const float* Wl2  = (const float*)d_in[8];
    const float* bl2  = (const float*)d_in[9];
    const float* Wr2  = (const float*)d_in[10];
    const float* br2  = (const float*)d_in[11];
    const float* att2 = (const float*)d_in[12];
    const float* b2   = (const float*)d_in[13];

    const int N = in_sizes[0] / 128;
    const int E = in_sizes[1] / 2;
    const int* src = eidx;
    const int* dst = eidx + E;

    const int nBlk = (N + 255) / 256;

    // workspace layout
    size_t NF = (size_t)N * 128;
    short* xl16 = (short*)d_ws;               // bf16 xl plane [N][128]
    float* bufB = (float*)(xl16 + NF);        // xr fp32
    float* bufC = bufB + NF;                  // h fp32 (layer-1 out)
    int* deg8      = (int*)(bufC + NF);       // [8][N]
    int* pub       = deg8 + 8 * (size_t)N;    // [nBlk] (zeroed with deg8)
    int* row_ptr   = pub + nBlk;              // [N+1]
    int* rpb       = row_ptr + (N + 1);       // [8][N]
    unsigned short* rank16 = (unsigned short*)(rpb + 8 * (size_t)N);  // [E]
    unsigned short* csr16  = rank16 + E;      // [E]
    short* wt      = (short*)(csr16 + E);     // 4 matrices x (hi+lo) x 16384

    float* outF = (float*)d_out;

    const int nCnt = (E + 255) / 256;
    const int gemmBlocks = (N + 31) / 32;
    int fusedGrid = 3 * gemmBlocks;
    if (nCnt > 2 * gemmBlocks) fusedGrid += nCnt - 2 * gemmBlocks;
    dim3 aggGrid((N + 3) / 4);

    // 1. W prep + zero deg8+pub (contiguous)
    prep_zero_kernel<<<32, 256, 0, stream>>>(Wl1, Wr1, Wl2, Wr2, wt, deg8, 8 * N + nBlk);
    // 2. GEMM layer 1 ||| degree count (interleaved roles, co-resident)
    gemm1_count_kernel<<<fusedGrid, 256, 0, stream>>>(
        x, wt, bl1, xl16, br1, bufB, N, gemmBlocks, dst, deg8, rank16, E, N);
    // 3. single-pass scan (publish + lookback)
    scan_fused_kernel<<<nBlk, 256, 0, stream>>>(deg8, pub, row_ptr, rpb, N, nBlk);
    // 4. scatter
    scatter_edges_kernel<<<nCnt, 256, 0, stream>>>(src, dst, rpb, rank16, csr16, E, N);
    // 5. layer-1 aggregate
    gat_aggregate_kernel<<<aggGrid, 256, 0, stream>>>(xl16, bufB, att1, b1, row_ptr, csr16,
                                                      bufC, N, 1);
    // 6-7. layer 2
    gemm_mfma_dual32_kernel<<<gemmBlocks, 256, 0, stream>>>(bufC, wt + 2 * 2 * 16384, bl2, xl16,
                                                            br2, bufB, N);
    gat_aggregate_kernel<<<aggGrid, 256, 0, stream>>>(xl16, bufB, att2, b2, row_ptr, csr16,
                                                      outF, N, 0);
}

// Round 15
// 283.200 us; speedup vs baseline: 1.0662x; 1.0047x over previous
//
#include <hip/hip_runtime.h>
#include <math.h>

// ---------------------------------------------------------------------------
// GATv2 2-layer GNN, fp32 in/out. N=50000, E=800000, F=128.
// 7 dispatches: prep_zero (W split + zero deg8+pub) -> [GEMM1 ||| count]
//   (interleaved roles 1:2) -> scan_fused (single-pass publish+lookback) ->
//   scatter (atomic-free, u16 csr) -> agg1 -> GEMM2 -> agg2
// r8: xl bf16 RNE. r9: atomic-free u16 scatter. r13: coalesced GEMM epilogue
//   + interleaved fusion. r14: single-pass scan, packed bf16 extract.
// r15: histogram slice = blockIdx&7 (TRUE XCD alignment -- r11 used the edge
//   chunk index, which does NOT track the executing XCD, so atomic lines
//   still ping-ponged). Slice is packed into rank16 bits 13..15 so scatter
//   can decode it (rank < 8192 holds for any plausible degree).
// Falsified: grid.sync fusion (r5), split-operand GEMM (r4), agg SW-pipeline
//   (r1/r2), 1-block scan (r6), GEMM tile size (r9/r10), concat fusion (r12).
// ---------------------------------------------------------------------------

typedef short bf16x8 __attribute__((ext_vector_type(8)));
typedef float f32x4 __attribute__((ext_vector_type(4)));

#define LDK 136
#define SMEM_BYTES (2 * 32 * LDK * 2)   // 17408 B staging; epilogue reuses it

// ---------------------------------------------------------------------------
// prep_zero: 32 blocks. Splits the 4 W matrices into bf16 hi/lo [n][k]
// planes AND zeroes deg8+pub (contiguous; replaces the memset dispatch).
// ---------------------------------------------------------------------------
__global__ __launch_bounds__(256) void prep_zero_kernel(
    const float* __restrict__ W0, const float* __restrict__ W1,
    const float* __restrict__ W2, const float* __restrict__ W3,
    short* __restrict__ wt, int* __restrict__ zbase, int ztotal) {
    int b = blockIdx.x;                  // 0..31
    for (int j = b * 256 + threadIdx.x; j < ztotal; j += 32 * 256) zbase[j] = 0;
    int mat = b >> 3, chunk = b & 7;
    const float* W = (mat == 0) ? W0 : (mat == 1) ? W1 : (mat == 2) ? W2 : W3;
    short* hi = wt + (size_t)mat * 2 * 16384;
    short* lo = hi + 16384;
    int i0 = chunk * 2048;
    for (int i = i0 + threadIdx.x; i < i0 + 2048; i += 256) {
        int k = i >> 7, n = i & 127;
        float x = W[i];
        unsigned u = __float_as_uint(x);
        unsigned hu = u & 0xFFFF0000u;
        float lf = x - __uint_as_float(hu);
        hi[n * 128 + k] = (short)(hu >> 16);
        lo[n * 128 + k] = (short)(__float_as_uint(lf) >> 16);
    }
}

// ---------------------------------------------------------------------------
// One-barrier split-bf16 MFMA GEMM body, dual-output 32x256 tile:
//   xl-plane (p=0) -> bf16 RNE [Nrows][128]; xr-plane (p=1) -> fp32.
// Epilogue: LDS-staged coalesced writes (r13).
// ---------------------------------------------------------------------------
__device__ __forceinline__ void gemm_dual32_body(
    int bx, const float* __restrict__ X, const short* __restrict__ wtL,
    const float* __restrict__ b0, short* __restrict__ out0bf,
    const float* __restrict__ b1, float* __restrict__ out1,
    int Nrows, char* smem) {
    short (*Ahi)[LDK] = (short (*)[LDK])smem;
    short (*Alo)[LDK] = (short (*)[LDK])(smem + 32 * LDK * 2);

    int tid = threadIdx.x;
    int w = tid >> 6, lane = tid & 63, q = lane >> 4, tr = lane & 15;
    int m0 = bx * 32;
    int n0 = w * 32;

    // B frags for chunk 0, issued before staging/barrier (L2 overlap)
    bf16x8 bh[4], bl[4];
    #pragma unroll
    for (int p = 0; p < 2; ++p) {
        const short* base = wtL + (size_t)p * 2 * 16384;
        #pragma unroll
        for (int nt = 0; nt < 2; ++nt) {
            size_t boff = (size_t)(n0 + nt * 16 + tr) * 128 + q * 8;
            bh[p * 2 + nt] = *(const bf16x8*)&base[boff];
            bl[p * 2 + nt] = *(const bf16x8*)&base[16384 + boff];
        }
    }

    // phase 1: stage 32x128 A-tile, 16 floats per thread
    {
        int srow = tid >> 3;            // 0..31
        int c0 = (tid & 7) * 16;        // 0,16,...,112
        int gr = m0 + srow; if (gr >= Nrows) gr = Nrows - 1;
        const float* xp = &X[(size_t)gr * 128 + c0];
        float4 v[4];
        #pragma unroll
        for (int j = 0; j < 4; ++j) v[j] = *(const float4*)(xp + j * 4);
        #pragma unroll
        for (int j = 0; j < 2; ++j) {
            bf16x8 hv, lv;
            #pragma unroll
            for (int k = 0; k < 2; ++k) {
                float4 vv = v[j * 2 + k];
                float f[4] = {vv.x, vv.y, vv.z, vv.w};
                #pragma unroll
                for (int e = 0; e < 4; ++e) {
                    unsigned u = __float_as_uint(f[e]);
                    unsigned hu = u & 0xFFFF0000u;
                    float lf = f[e] - __uint_as_float(hu);
                    hv[k * 4 + e] = (short)(hu >> 16);
                    lv[k * 4 + e] = (short)(__float_as_uint(lf) >> 16);
                }
            }
            *(bf16x8*)&Ahi[srow][c0 + j * 8] = hv;
            *(bf16x8*)&Alo[srow][c0 + j * 8] = lv;
        }
    }
    __syncthreads();

    // phase 2: pure compute
    f32x4 acc[2][4];   // [mt][p*2+nt]
    #pragma unroll
    for (int a = 0; a < 2; ++a)
        #pragma unroll
        for (int b = 0; b < 4; ++b) acc[a][b] = (f32x4){0.f, 0.f, 0.f, 0.f};

    for (int kc = 0; kc < 128; kc += 32) {
        #pragma unroll
        for (int mt = 0; mt < 2; ++mt) {
            bf16x8 ah = *(const bf16x8*)&Ahi[mt * 16 + tr][kc + q * 8];
            bf16x8 al = *(const bf16x8*)&Alo[mt * 16 + tr][kc + q * 8];
            #pragma unroll
            for (int j = 0; j < 4; ++j) {
                acc[mt][j] = __builtin_amdgcn_mfma_f32_16x16x32_bf16(ah, bh[j], acc[mt][j], 0, 0, 0);
                acc[mt][j] = __builtin_amdgcn_mfma_f32_16x16x32_bf16(ah, bl[j], acc[mt][j], 0, 0, 0);
                acc[mt][j] = __builtin_amdgcn_mfma_f32_16x16x32_bf16(al, bh[j], acc[mt][j], 0, 0, 0);
            }
        }
        if (kc < 96) {
            #pragma unroll
            for (int p = 0; p < 2; ++p) {
                const short* base = wtL + (size_t)p * 2 * 16384;
                #pragma unroll
                for (int nt = 0; nt < 2; ++nt) {
                    size_t boff = (size_t)(n0 + nt * 16 + tr) * 128 + (kc + 32) + q * 8;
                    bh[p * 2 + nt] = *(const bf16x8*)&base[boff];
                    bl[p * 2 + nt] = *(const bf16x8*)&base[16384 + boff];
                }
            }
        }
    }

    // --- epilogue: LDS-staged coalesced writes ---
    int orow = tid >> 3;             // 0..31
    int oc0 = (tid & 7) * 16;        // 0..112
    int gr = m0 + orow;

    float (*Ofp)[132] = (float (*)[132])smem;
    __syncthreads();                 // staging reads done
    #pragma unroll
    for (int nt = 0; nt < 2; ++nt) {
        float bv1 = b1[n0 + nt * 16 + tr];
        #pragma unroll
        for (int mt = 0; mt < 2; ++mt)
            #pragma unroll
            for (int r = 0; r < 4; ++r)
                Ofp[mt * 16 + q * 4 + r][n0 + nt * 16 + tr] = acc[mt][2 + nt][r] + bv1;
    }
    __syncthreads();
    if (gr < Nrows) {
        #pragma unroll
        for (int j = 0; j < 4; ++j)
            *(float4*)&out1[(size_t)gr * 128 + oc0 + j * 4] = *(float4*)&Ofp[orow][oc0 + j * 4];
    }
    __syncthreads();

    short (*Obf)[136] = (short (*)[136])smem;
    #pragma unroll
    for (int nt = 0; nt < 2; ++nt) {
        float bv0 = b0[n0 + nt * 16 + tr];
        #pragma unroll
        for (int mt = 0; mt < 2; ++mt)
            #pragma unroll
            for (int r = 0; r < 4; ++r) {
                float v0 = acc[mt][nt][r] + bv0;
                unsigned u = __float_as_uint(v0);
                unsigned rb = (u + 0x7FFFu + ((u >> 16) & 1u)) >> 16;
                Obf[mt * 16 + q * 4 + r][n0 + nt * 16 + tr] = (short)rb;
            }
    }
    __syncthreads();
    if (gr < Nrows) {
        *(bf16x8*)&out0bf[(size_t)gr * 128 + oc0]     = *(bf16x8*)&Obf[orow][oc0];
        *(bf16x8*)&out0bf[(size_t)gr * 128 + oc0 + 8] = *(bf16x8*)&Obf[orow][oc0 + 8];
    }
}

// --- standalone GEMM (layer 2) ---
__global__ __launch_bounds__(256) void gemm_mfma_dual32_kernel(
    const float* __restrict__ X, const short* __restrict__ wtL,
    const float* __restrict__ b0, short* __restrict__ out0bf,
    const float* __restrict__ b1, float* __restrict__ out1, int Nrows) {
    __shared__ __attribute__((aligned(16))) char smem[SMEM_BYTES];
    gemm_dual32_body(blockIdx.x, X, wtL, b0, out0bf, b1, out1, Nrows, smem);
}

// --- fused, INTERLEAVED: role = bx%3 (0 -> GEMM block bx/3; 1,2 -> count
//     block bx/3*2+(role-1)). Count slice = blockIdx&7 (true XCD affinity);
//     slice packed into rank16 bits 13..15 for the scatter to decode. ---
__global__ __launch_bounds__(256) void gemm1_count_kernel(
    const float* __restrict__ X, const short* __restrict__ wtL,
    const float* __restrict__ b0, short* __restrict__ out0bf,
    const float* __restrict__ b1, float* __restrict__ out1,
    int Nrows, int gemmBlocks,
    const int* __restrict__ dst, int* __restrict__ deg8,
    unsigned short* __restrict__ rank16, int E, int N) {
    __shared__ __attribute__((aligned(16))) char smem[SMEM_BYTES];
    int bx = blockIdx.x;
    int base3 = 3 * gemmBlocks;
    int cb;
    if (bx < base3) {
        int role = bx % 3, g = bx / 3;
        if (role == 0) {
            gemm_dual32_body(g, X, wtL, b0, out0bf, b1, out1, Nrows, smem);
            return;
        }
        cb = g * 2 + (role - 1);
    } else {
        cb = 2 * gemmBlocks + (bx - base3);   // tail count blocks (if any)
    }
    int i = cb * 256 + threadIdx.x;
    if (i < E) {
        int slice = bx & 7;                  // block->XCD round-robin affinity
        int r = atomicAdd(&deg8[(size_t)slice * N + dst[i]], 1);
        rank16[i] = (unsigned short)(r | (slice << 13));
    }
}

// ---------------------------------------------------------------------------
// Single-pass scan (publish + lookback). 196 blocks, all co-resident;
// publish-before-spin => deadlock-free. pub[] pre-zeroed; published value
// = bsum+1. Outputs row_ptr[0..n], rpb[s][node] = row_ptr + slice-prefix.
// ---------------------------------------------------------------------------
__global__ __launch_bounds__(256) void scan_fused_kernel(
    const int* __restrict__ deg8, int* __restrict__ pub,
    int* __restrict__ row_ptr, int* __restrict__ rpb, int n, int nBlk) {
    __shared__ int sA[4], sB[4];
    __shared__ int sBsum;
    int tid = threadIdx.x, lane = tid & 63, wid = tid >> 6;
    int idx = blockIdx.x * 256 + tid;

    int b8[8];
    int tot = 0;
    if (idx < n) {
        #pragma unroll
        for (int s = 0; s < 8; ++s) {
            int v = deg8[(size_t)s * n + idx];
            b8[s] = tot;
            tot += v;
        }
    }

    int v = tot;
    #pragma unroll
    for (int off = 32; off > 0; off >>= 1) v += __shfl_xor(v, off);
    if (lane == 0) sA[wid] = v;
    __syncthreads();
    if (tid == 0) {
        int bs = sA[0] + sA[1] + sA[2] + sA[3];
        sBsum = bs;
        atomicExch(&pub[blockIdx.x], bs + 1);
    }
    __syncthreads();
    int bsum = sBsum;

    int pv = 0;
    if (tid < (int)blockIdx.x) {
        while ((pv = atomicAdd(&pub[tid], 0)) == 0) {}
        pv -= 1;
    }
    int pr = pv;
    #pragma unroll
    for (int off = 32; off > 0; off >>= 1) pr += __shfl_xor(pr, off);
    if (lane == 0) sB[wid] = pr;
    __syncthreads();
    int off0 = sB[0] + sB[1] + sB[2] + sB[3];

    int incl = tot;
    #pragma unroll
    for (int off = 1; off < 64; off <<= 1) {
        int t = __shfl_up(incl, off);
        if (lane >= off) incl += t;
    }
    if (lane == 63) sA[wid] = incl;
    __syncthreads();
    int woff = 0;
    #pragma unroll
    for (int w = 0; w < 4; ++w) woff += (w < wid) ? sA[w] : 0;
    int excl = off0 + woff + (incl - tot);
    if (idx < n) {
        row_ptr[idx] = excl;
        #pragma unroll
        for (int s = 0; s < 8; ++s)
            rpb[(size_t)s * n + idx] = excl + b8[s];
    }
    if ((int)blockIdx.x == nBlk - 1 && tid == 0) row_ptr[n] = off0 + bsum;
}

// --- atomic-free scatter: slice/rank decoded from rank16 (slice in bits
//     13..15, rank in bits 0..12); pos = rpb[slice][dst] + rank ---
__global__ void scatter_edges_kernel(const int* __restrict__ src, const int* __restrict__ dst,
                                     const int* __restrict__ rpb,
                                     const unsigned short* __restrict__ rank16,
                                     unsigned short* __restrict__ csr16, int E, int N) {
    int i = blockIdx.x * blockDim.x + threadIdx.x;
    if (i < E) {
        int d = dst[i];
        unsigned rv = rank16[i];
        int slice = rv >> 13;
        int r = rv & 0x1FFF;
        int pos = rpb[(size_t)slice * N + d] + r;
        csr16[pos] = (unsigned short)src[i];
    }
}

// ---------------------------------------------------------------------------
// Aggregation v7: xl is bf16 [N][128], csr entries u16. 16-lane groups,
// 4 edges/wave. Packed bf16 extraction (lo = d<<16, hi = d&0xFFFF0000).
// leaky = fmaxf(t, 0.2t). Per-edge reduce: 4 intra-16 shfl_xor (DPP).
// ---------------------------------------------------------------------------
__global__ __launch_bounds__(256) void gat_aggregate_kernel(
    const short* __restrict__ xl16, const float* __restrict__ xr,
    const float* __restrict__ att, const float* __restrict__ bias,
    const int* __restrict__ row_ptr, const unsigned short* __restrict__ csr16,
    float* __restrict__ out, int N, int applyRelu) {
    int wid = threadIdx.x >> 6;      // 0..3 -> node within block
    int lane = threadIdx.x & 63;
    int qlane = lane & 15;
    int qid = lane >> 4;
    int node = blockIdx.x * 4 + wid;
    if (node >= N) return;

    const uint4* xlb = (const uint4*)xl16;     // row = 16 x uint4
    float4 xrA = ((const float4*)xr)[(size_t)node * 32 + qlane * 2];
    float4 xrB = ((const float4*)xr)[(size_t)node * 32 + qlane * 2 + 1];
    float4 atA = ((const float4*)att)[qlane * 2];
    float4 atB = ((const float4*)att)[qlane * 2 + 1];

    int beg = row_ptr[node];
    int end = row_ptr[node + 1];

    float dsum = 0.f;
    float4 accA = {0.f, 0.f, 0.f, 0.f};
    float4 accB = {0.f, 0.f, 0.f, 0.f};

    for (int cbase = beg; cbase < end; cbase += 64) {
        int cnt = end - cbase;
        if (cnt > 64) cnt = 64;
        int myidx = (lane < cnt) ? (int)csr16[cbase + lane] : 0;  // coalesced u16
        int nq = (cnt + 3) >> 2;                                  // quads of 4 edges

        for (int g = 0; g < nq; ++g) {
            int eidx = 4 * g + qid;
            int s = __shfl(myidx, eidx);
            uint4 md = xlb[((size_t)s << 4) + qlane];
            float4 vA, vB;
            vA.x = __uint_as_float(md.x << 16);
            vA.y = __uint_as_float(md.x & 0xFFFF0000u);
            vA.z = __uint_as_float(md.y << 16);
            vA.w = __uint_as_float(md.y & 0xFFFF0000u);
            vB.x = __uint_as_float(md.z << 16);
            vB.y = __uint_as_float(md.z & 0xFFFF0000u);
            vB.z = __uint_as_float(md.w << 16);
            vB.w = __uint_as_float(md.w & 0xFFFF0000u);

            float t, p;
            t = vA.x + xrA.x; t = fmaxf(t, 0.2f * t); p = t * atA.x;
            t = vA.y + xrA.y; t = fmaxf(t, 0.2f * t); p = fmaf(t, atA.y, p);
            t = vA.z + xrA.z; t = fmaxf(t, 0.2f * t); p = fmaf(t, atA.z, p);
            t = vA.w + xrA.w; t = fmaxf(t, 0.2f * t); p = fmaf(t, atA.w, p);
            t = vB.x + xrB.x; t = fmaxf(t, 0.2f * t); p = fmaf(t, atB.x, p);
            t = vB.y + xrB.y; t = fmaxf(t, 0.2f * t); p = fmaf(t, atB.y, p);
            t = vB.z + xrB.z; t = fmaxf(t, 0.2f * t); p = fmaf(t, atB.z, p);
            t = vB.w + xrB.w; t = fmaxf(t, 0.2f * t); p = fmaf(t, atB.w, p);

            p += __shfl_xor(p, 1);
            p += __shfl_xor(p, 2);
            p += __shfl_xor(p, 4);
            p += __shfl_xor(p, 8);

            float e = (eidx < cnt) ? __expf(p) : 0.f;
            dsum += e;
            accA.x = fmaf(e, vA.x, accA.x);
            accA.y = fmaf(e, vA.y, accA.y);
            accA.z = fmaf(e, vA.z, accA.z);
            accA.w = fmaf(e, vA.w, accA.w);
            accB.x = fmaf(e, vB.x, accB.x);
            accB.y = fmaf(e, vB.y, accB.y);
            accB.z = fmaf(e, vB.z, accB.z);
            accB.w = fmaf(e, vB.w, accB.w);
        }
    }

    #pragma unroll
    for (int off = 16; off <= 32; off <<= 1) {
        dsum += __shfl_xor(dsum, off);
        accA.x += __shfl_xor(accA.x, off);
        accA.y += __shfl_xor(accA.y, off);
        accA.z += __shfl_xor(accA.z, off);
        accA.w += __shfl_xor(accA.w, off);
        accB.x += __shfl_xor(accB.x, off);
        accB.y += __shfl_xor(accB.y, off);
        accB.z += __shfl_xor(accB.z, off);
        accB.w += __shfl_xor(accB.w, off);
    }

    float inv = dsum > 0.f ? 1.f / dsum : 0.f;
    float4 bvA = ((const float4*)bias)[qlane * 2];
    float4 bvB = ((const float4*)bias)[qlane * 2 + 1];
    float4 oA, oB;
    oA.x = accA.x * inv + bvA.x; oA.y = accA.y * inv + bvA.y;
    oA.z = accA.z * inv + bvA.z; oA.w = accA.w * inv + bvA.w;
    oB.x = accB.x * inv + bvB.x; oB.y = accB.y * inv + bvB.y;
    oB.z = accB.z * inv + bvB.z; oB.w = accB.w * inv + bvB.w;
    if (applyRelu) {
        oA.x = fmaxf(oA.x, 0.f); oA.y = fmaxf(oA.y, 0.f);
        oA.z = fmaxf(oA.z, 0.f); oA.w = fmaxf(oA.w, 0.f);
        oB.x = fmaxf(oB.x, 0.f); oB.y = fmaxf(oB.y, 0.f);
        oB.z = fmaxf(oB.z, 0.f); oB.w = fmaxf(oB.w, 0.f);
    }
    if (lane < 16) {
        ((float4*)out)[(size_t)node * 32 + qlane * 2] = oA;
        ((float4*)out)[(size_t)node * 32 + qlane * 2 + 1] = oB;
    }
}

// ---------------------------------------------------------------------------

extern "C" void kernel_launch(void* const* d_in, const int* in_sizes, int n_in,
                              void* d_out, int out_size, void* d_ws, size_t ws_size,
                              hipStream_t stream) {
    const float* x    = (const float*)d_in[0];
    const int* eidx   = (const int*)d_in[1];
    const float* Wl1  = (const float*)d_in[2];
    const float* bl1  = (const float*)d_in[3];
    const float* Wr1  = (const float*)d_in[4];
    const float* br1  = (const float*)d_in[5];
    const float* att1 = (const float*)d_in[6];
    const float* b1   = (const float*)d_in[7];
    const float* Wl2  = (const float*)d_in[8];
    const float* bl2  = (const float*)d_in[9];
    const float* Wr2  = (const float*)d_in[10];
    const float* br2  = (const float*)d_in[11];
    const float* att2 = (const float*)d_in[12];
    const float* b2   = (const float*)d_in[13];

    const int N = in_sizes[0] / 128;
    const int E = in_sizes[1] / 2;
    const int* src = eidx;
    const int* dst = eidx + E;

    const int nBlk = (N + 255) / 256;

    // workspace layout
    size_t NF = (size_t)N * 128;
    short* xl16 = (short*)d_ws;               // bf16 xl plane [N][128]
    float* bufB = (float*)(xl16 + NF);        // xr fp32
    float* bufC = bufB + NF;                  // h fp32 (layer-1 out)
    int* deg8      = (int*)(bufC + NF);       // [8][N]
    int* pub       = deg8 + 8 * (size_t)N;    // [nBlk] (zeroed with deg8)
    int* row_ptr   = pub + nBlk;              // [N+1]
    int* rpb       = row_ptr + (N + 1);       // [8][N]
    unsigned short* rank16 = (unsigned short*)(rpb + 8 * (size_t)N);  // [E]
    unsigned short* csr16  = rank16 + E;      // [E]
    short* wt      = (short*)(csr16 + E);     // 4 matrices x (hi+lo) x 16384

    float* outF = (float*)d_out;

    const int nCnt = (E + 255) / 256;
    const int gemmBlocks = (N + 31) / 32;
    int fusedGrid = 3 * gemmBlocks;
    if (nCnt > 2 * gemmBlocks) fusedGrid += nCnt - 2 * gemmBlocks;
    dim3 aggGrid((N + 3) / 4);

    // 1. W prep + zero deg8+pub (contiguous)
    prep_zero_kernel<<<32, 256, 0, stream>>>(Wl1, Wr1, Wl2, Wr2, wt, deg8, 8 * N + nBlk);
    // 2. GEMM layer 1 ||| degree count (interleaved roles, co-resident)
    gemm1_count_kernel<<<fusedGrid, 256, 0, stream>>>(
        x, wt, bl1, xl16, br1, bufB, N, gemmBlocks, dst, deg8, rank16, E, N);
    // 3. single-pass scan (publish + lookback)
    scan_fused_kernel<<<nBlk, 256, 0, stream>>>(deg8, pub, row_ptr, rpb, N, nBlk);
    // 4. scatter
    scatter_edges_kernel<<<nCnt, 256, 0, stream>>>(src, dst, rpb, rank16, csr16, E, N);
    // 5. layer-1 aggregate
    gat_aggregate_kernel<<<aggGrid, 256, 0, stream>>>(xl16, bufB, att1, b1, row_ptr, csr16,
                                                      bufC, N, 1);
    // 6-7. layer 2
    gemm_mfma_dual32_kernel<<<gemmBlocks, 256, 0, stream>>>(bufC, wt + 2 * 2 * 16384, bl2, xl16,
                                                            br2, bufB, N);
    gat_aggregate_kernel<<<aggGrid, 256, 0, stream>>>(xl16, bufB, att2, b2, row_ptr, csr16,
                                                      outF, N, 0);
}